// Round 1
// baseline (1207.227 us; speedup 1.0000x reference)
//
#include <hip/hip_runtime.h>
#include <math.h>

#define BB 8
#define CC 64
#define LHH 128
#define LWW 128
#define HHH 64
#define HWW 64

// ---------------------------------------------------------------------------
// K1: depthwise 3x3 conv on high_feature -> h_small (B,C,64,64)
// ---------------------------------------------------------------------------
__global__ __launch_bounds__(256) void dw_high_kernel(
    const float* __restrict__ hf, const float* __restrict__ w,
    float* __restrict__ out) {
  int t = blockIdx.x * blockDim.x + threadIdx.x;
  if (t >= BB * CC * HHH * HWW) return;
  int x = t & 63;
  int y = (t >> 6) & 63;
  int c = (t >> 12) & 63;
  int b = t >> 18;
  const float* img = hf + ((size_t)(b * CC + c)) * (HHH * HWW);
  const float* wc = w + c * 9;
  float acc = 0.f;
#pragma unroll
  for (int dy = 0; dy < 3; ++dy) {
    int yy = y + dy - 1;
    if (yy < 0 || yy >= HHH) continue;
#pragma unroll
    for (int dx = 0; dx < 3; ++dx) {
      int xx = x + dx - 1;
      if (xx < 0 || xx >= HWW) continue;
      acc = fmaf(img[yy * HWW + xx], wc[dy * 3 + dx], acc);
    }
  }
  out[t] = acc;
}

// ---------------------------------------------------------------------------
// K2: per (b,y,x): loop c: l = depthwise(low), h = bilinear-up(h_small);
//     write sum = l+h; accumulate channel mean/max stats -> gate_in (B,4,H,W)
// ---------------------------------------------------------------------------
__global__ __launch_bounds__(256) void fuse_sum_stats_kernel(
    const float* __restrict__ low, const float* __restrict__ hsm,
    const float* __restrict__ wl, float* __restrict__ sumbuf,
    float* __restrict__ gate_in) {
  int t = blockIdx.x * blockDim.x + threadIdx.x;
  if (t >= BB * LHH * LWW) return;
  int x = t & 127;
  int y = (t >> 7) & 127;
  int b = t >> 14;

  // jax.image.resize bilinear 64->128 half-pixel: src = (dst+0.5)*0.5 - 0.5
  float sy = 0.5f * y - 0.25f;
  float sx = 0.5f * x - 0.25f;
  float y0f = floorf(sy), x0f = floorf(sx);
  float wy = sy - y0f, wx = sx - x0f;
  int iy0 = (int)y0f, ix0 = (int)x0f;
  int iy0c = max(0, min(HHH - 1, iy0));
  int iy1c = max(0, min(HHH - 1, iy0 + 1));
  int ix0c = max(0, min(HWW - 1, ix0));
  int ix1c = max(0, min(HWW - 1, ix0 + 1));

  float hmean = 0.f, lmean = 0.f;
  float hmax = -3.402823466e+38f, lmax = -3.402823466e+38f;

  for (int c = 0; c < CC; ++c) {
    // depthwise low
    const float* limg = low + ((size_t)(b * CC + c)) * (LHH * LWW);
    const float* wc = wl + c * 9;
    float l = 0.f;
#pragma unroll
    for (int dy = 0; dy < 3; ++dy) {
      int yy = y + dy - 1;
      if (yy < 0 || yy >= LHH) continue;
#pragma unroll
      for (int dx = 0; dx < 3; ++dx) {
        int xx = x + dx - 1;
        if (xx < 0 || xx >= LWW) continue;
        l = fmaf(limg[yy * LWW + xx], wc[dy * 3 + dx], l);
      }
    }
    // bilinear upsample of h_small
    const float* himg = hsm + ((size_t)(b * CC + c)) * (HHH * HWW);
    float h00 = himg[iy0c * HWW + ix0c];
    float h01 = himg[iy0c * HWW + ix1c];
    float h10 = himg[iy1c * HWW + ix0c];
    float h11 = himg[iy1c * HWW + ix1c];
    float h = (1.f - wy) * ((1.f - wx) * h00 + wx * h01) +
              wy * ((1.f - wx) * h10 + wx * h11);

    sumbuf[((size_t)(b * CC + c)) * (LHH * LWW) + y * LWW + x] = l + h;
    hmean += h;
    lmean += l;
    hmax = fmaxf(hmax, h);
    lmax = fmaxf(lmax, l);
  }
  int p = (b * 4) * (LHH * LWW) + y * LWW + x;
  gate_in[p] = hmean * (1.0f / CC);
  gate_in[p + LHH * LWW] = lmean * (1.0f / CC);
  gate_in[p + 2 * LHH * LWW] = hmax;
  gate_in[p + 3 * LHH * LWW] = lmax;
}

// ---------------------------------------------------------------------------
// K3: gate conv 4->1 3x3 + sigmoid -> gates (B,1,H,W)
// ---------------------------------------------------------------------------
__global__ __launch_bounds__(256) void gate_kernel(
    const float* __restrict__ gate_in, const float* __restrict__ wg,
    float* __restrict__ gates) {
  int t = blockIdx.x * blockDim.x + threadIdx.x;
  if (t >= BB * LHH * LWW) return;
  int x = t & 127;
  int y = (t >> 7) & 127;
  int b = t >> 14;
  float acc = 0.f;
#pragma unroll
  for (int ic = 0; ic < 4; ++ic) {
    const float* img = gate_in + ((size_t)(b * 4 + ic)) * (LHH * LWW);
    const float* wc = wg + ic * 9;
#pragma unroll
    for (int dy = 0; dy < 3; ++dy) {
      int yy = y + dy - 1;
      if (yy < 0 || yy >= LHH) continue;
#pragma unroll
      for (int dx = 0; dx < 3; ++dx) {
        int xx = x + dx - 1;
        if (xx < 0 || xx >= LWW) continue;
        acc = fmaf(img[yy * LWW + xx], wc[dy * 3 + dx], acc);
      }
    }
  }
  gates[t] = 1.0f / (1.0f + expf(-acc));
}

// ---------------------------------------------------------------------------
// zero-padded bilinear sample (reference's per-tap valid mask)
// ---------------------------------------------------------------------------
__device__ __forceinline__ float bilin0(const float* __restrict__ img, int H,
                                        int W, float gx, float gy) {
  float x0f = floorf(gx), y0f = floorf(gy);
  float wx1 = gx - x0f, wy1 = gy - y0f;
  int x0 = (int)x0f, y0 = (int)y0f;
  float r = 0.f;
  {
    int xi = x0, yi = y0;
    if (xi >= 0 && xi < W && yi >= 0 && yi < H)
      r = fmaf(img[yi * W + xi], (1.f - wx1) * (1.f - wy1), r);
  }
  {
    int xi = x0 + 1, yi = y0;
    if (xi >= 0 && xi < W && yi >= 0 && yi < H)
      r = fmaf(img[yi * W + xi], wx1 * (1.f - wy1), r);
  }
  {
    int xi = x0, yi = y0 + 1;
    if (xi >= 0 && xi < W && yi >= 0 && yi < H)
      r = fmaf(img[yi * W + xi], (1.f - wx1) * wy1, r);
  }
  {
    int xi = x0 + 1, yi = y0 + 1;
    if (xi >= 0 && xi < W && yi >= 0 && yi < H)
      r = fmaf(img[yi * W + xi], wx1 * wy1, r);
  }
  return r;
}

// ---------------------------------------------------------------------------
// K4 (fused heavy kernel): per (b,c) and 16x16 spatial tile:
//   - compute the 4 needed flow channels (2c, 2c+1, 128+2c, 129+2c) via
//     3x3 conv over all 64 input channels of sumbuf (LDS-staged tile,
//     scalar-loaded weights)
//   - bilinear-warp high_feature and low_feature with zero-pad taps
//   - blend with gate
// ---------------------------------------------------------------------------
__global__ __launch_bounds__(256) void flow_warp_combine_kernel(
    const float* __restrict__ sumbuf, const float* __restrict__ wflow,
    const float* __restrict__ low, const float* __restrict__ high,
    const float* __restrict__ gates, float* __restrict__ out) {
  const int c = blockIdx.x;      // output channel
  const int tile = blockIdx.y;   // 8x8 tiles of 16x16
  const int b = blockIdx.z;
  const int ty0 = (tile >> 3) * 16;
  const int tx0 = (tile & 7) * 16;
  const int tx = threadIdx.x, ty = threadIdx.y;
  const int tid = ty * 16 + tx;

  __shared__ float tileS[16][18][20];  // [ch_chunk][row][col(+pad)]

  const float* w0 = wflow + (size_t)(2 * c) * 576;
  const float* w1 = wflow + (size_t)(2 * c + 1) * 576;
  const float* w2 = wflow + (size_t)(128 + 2 * c) * 576;
  const float* w3 = wflow + (size_t)(129 + 2 * c) * 576;

  float a0 = 0.f, a1 = 0.f, a2 = 0.f, a3 = 0.f;

  for (int cc = 0; cc < 4; ++cc) {
    const float* src = sumbuf + ((size_t)(b * CC + cc * 16)) * (LHH * LWW);
    for (int idx = tid; idx < 16 * 18 * 18; idx += 256) {
      int ci = idx / 324;
      int rem = idx - ci * 324;
      int r = rem / 18;
      int col = rem - r * 18;
      int gy = ty0 - 1 + r;
      int gx = tx0 - 1 + col;
      float v = 0.f;
      if (gy >= 0 && gy < LHH && gx >= 0 && gx < LWW)
        v = src[ci * (LHH * LWW) + gy * LWW + gx];
      tileS[ci][r][col] = v;
    }
    __syncthreads();
#pragma unroll 2
    for (int ci = 0; ci < 16; ++ci) {
      int wb = (cc * 16 + ci) * 9;
#pragma unroll
      for (int dy = 0; dy < 3; ++dy) {
#pragma unroll
        for (int dx = 0; dx < 3; ++dx) {
          float v = tileS[ci][ty + dy][tx + dx];
          int wi = wb + dy * 3 + dx;
          a0 = fmaf(v, w0[wi], a0);
          a1 = fmaf(v, w1[wi], a1);
          a2 = fmaf(v, w2[wi], a2);
          a3 = fmaf(v, w3[wi], a3);
        }
      }
    }
    __syncthreads();
  }

  const int y = ty0 + ty;
  const int x = tx0 + tx;
  // base grid: linspace(-1,1,128)[x] + flow/128
  float bx = -1.0f + x * (2.0f / 127.0f);
  float by = -1.0f + y * (2.0f / 127.0f);

  // high warp: input 64x64
  float gxh = (bx + a0 * (1.0f / 128.0f) + 1.0f) * 0.5f * (float)(HWW - 1);
  float gyh = (by + a1 * (1.0f / 128.0f) + 1.0f) * 0.5f * (float)(HHH - 1);
  float hwv =
      bilin0(high + ((size_t)(b * CC + c)) * (HHH * HWW), HHH, HWW, gxh, gyh);

  // low warp: input 128x128
  float gxl = (bx + a2 * (1.0f / 128.0f) + 1.0f) * 0.5f * (float)(LWW - 1);
  float gyl = (by + a3 * (1.0f / 128.0f) + 1.0f) * 0.5f * (float)(LHH - 1);
  float lwv =
      bilin0(low + ((size_t)(b * CC + c)) * (LHH * LWW), LHH, LWW, gxl, gyl);

  float g = gates[b * (LHH * LWW) + y * LWW + x];
  out[((size_t)(b * CC + c)) * (LHH * LWW) + y * LWW + x] =
      hwv * g + lwv * (1.0f - g);
}

// ---------------------------------------------------------------------------
extern "C" void kernel_launch(void* const* d_in, const int* in_sizes, int n_in,
                              void* d_out, int out_size, void* d_ws,
                              size_t ws_size, hipStream_t stream) {
  const float* low = (const float*)d_in[0];       // (8,64,128,128)
  const float* high = (const float*)d_in[1];      // (8,64,64,64)
  const float* w_conv_l = (const float*)d_in[2];  // (64,1,3,3)
  const float* w_conv_h = (const float*)d_in[3];  // (64,1,3,3)
  const float* w_flow = (const float*)d_in[4];    // (256,64,3,3)
  const float* w_gate = (const float*)d_in[5];    // (1,4,3,3)
  float* out = (float*)d_out;

  char* ws = (char*)d_ws;
  float* h_small = (float*)ws;                                  // 8 MiB
  float* sumbuf = (float*)(ws + 8388608);                       // 32 MiB
  float* gate_in = (float*)(ws + 8388608 + 33554432);           // 2 MiB
  float* gates = (float*)(ws + 8388608 + 33554432 + 2097152);   // 0.5 MiB

  dw_high_kernel<<<(BB * CC * HHH * HWW + 255) / 256, 256, 0, stream>>>(
      high, w_conv_h, h_small);
  fuse_sum_stats_kernel<<<(BB * LHH * LWW + 255) / 256, 256, 0, stream>>>(
      low, h_small, w_conv_l, sumbuf, gate_in);
  gate_kernel<<<(BB * LHH * LWW + 255) / 256, 256, 0, stream>>>(gate_in,
                                                                w_gate, gates);
  dim3 g5(CC, 64, BB), b5(16, 16);
  flow_warp_combine_kernel<<<g5, b5, 0, stream>>>(sumbuf, w_flow, low, high,
                                                  gates, out);
}

// Round 2
// 313.259 us; speedup vs baseline: 3.8538x; 3.8538x over previous
//
#include <hip/hip_runtime.h>
#include <math.h>

#define BB 8
#define CC 64
#define LHH 128
#define LWW 128
#define HHH 64
#define HWW 64

typedef __attribute__((ext_vector_type(8))) short short8v;
typedef __attribute__((ext_vector_type(4))) float f32x4;
typedef __attribute__((ext_vector_type(4))) unsigned int uint4v;
typedef __attribute__((ext_vector_type(2))) unsigned int uint2v;

#define BTS 584          // B_t row stride (shorts): 576 + 8 pad
#define SPITCH 16900     // 130*130 padded image
#define ALDS 40          // As row stride in shorts (80 B)

__device__ __forceinline__ unsigned short f2bf(float f) {
  unsigned u = __float_as_uint(f);
  unsigned r = (u + 0x7fffu + ((u >> 16) & 1u)) >> 16;
  return (unsigned short)r;
}
__device__ __forceinline__ float bf2f(unsigned short u) {
  return __uint_as_float(((unsigned)u) << 16);
}

// ---------------------------------------------------------------------------
// K1: depthwise 3x3 on high_feature -> h_small (B,C,64,64) fp32
// ---------------------------------------------------------------------------
__global__ __launch_bounds__(256) void dw_high_kernel(
    const float* __restrict__ hf, const float* __restrict__ w,
    float* __restrict__ out) {
  int t = blockIdx.x * blockDim.x + threadIdx.x;
  if (t >= BB * CC * HHH * HWW) return;
  int x = t & 63;
  int y = (t >> 6) & 63;
  int c = (t >> 12) & 63;
  int b = t >> 18;
  const float* img = hf + ((size_t)(b * CC + c)) * (HHH * HWW);
  const float* wc = w + c * 9;
  float acc = 0.f;
#pragma unroll
  for (int dy = 0; dy < 3; ++dy) {
    int yy = y + dy - 1;
    if (yy < 0 || yy >= HHH) continue;
#pragma unroll
    for (int dx = 0; dx < 3; ++dx) {
      int xx = x + dx - 1;
      if (xx < 0 || xx >= HWW) continue;
      acc = fmaf(img[yy * HWW + xx], wc[dy * 3 + dx], acc);
    }
  }
  out[t] = acc;
}

// ---------------------------------------------------------------------------
// K2: per (b,y,x): l=dw(low), h=up(h_small); write sum (bf16 padded and/or
//     fp32), accumulate gate stats.
// ---------------------------------------------------------------------------
__global__ __launch_bounds__(256) void fuse_sum_stats_kernel(
    const float* __restrict__ low, const float* __restrict__ hsm,
    const float* __restrict__ wl, unsigned short* __restrict__ sump_bf,
    float* __restrict__ sum_f32, float* __restrict__ gate_in) {
  int t = blockIdx.x * blockDim.x + threadIdx.x;
  if (t >= BB * LHH * LWW) return;
  int x = t & 127;
  int y = (t >> 7) & 127;
  int b = t >> 14;

  float sy = 0.5f * y - 0.25f;
  float sx = 0.5f * x - 0.25f;
  float y0f = floorf(sy), x0f = floorf(sx);
  float wy = sy - y0f, wx = sx - x0f;
  int iy0 = (int)y0f, ix0 = (int)x0f;
  int iy0c = max(0, min(HHH - 1, iy0));
  int iy1c = max(0, min(HHH - 1, iy0 + 1));
  int ix0c = max(0, min(HWW - 1, ix0));
  int ix1c = max(0, min(HWW - 1, ix0 + 1));

  float hmean = 0.f, lmean = 0.f;
  float hmax = -3.402823466e+38f, lmax = -3.402823466e+38f;

  for (int c = 0; c < CC; ++c) {
    const float* limg = low + ((size_t)(b * CC + c)) * (LHH * LWW);
    const float* wc = wl + c * 9;
    float l = 0.f;
#pragma unroll
    for (int dy = 0; dy < 3; ++dy) {
      int yy = y + dy - 1;
      if (yy < 0 || yy >= LHH) continue;
#pragma unroll
      for (int dx = 0; dx < 3; ++dx) {
        int xx = x + dx - 1;
        if (xx < 0 || xx >= LWW) continue;
        l = fmaf(limg[yy * LWW + xx], wc[dy * 3 + dx], l);
      }
    }
    const float* himg = hsm + ((size_t)(b * CC + c)) * (HHH * HWW);
    float h00 = himg[iy0c * HWW + ix0c];
    float h01 = himg[iy0c * HWW + ix1c];
    float h10 = himg[iy1c * HWW + ix0c];
    float h11 = himg[iy1c * HWW + ix1c];
    float h = (1.f - wy) * ((1.f - wx) * h00 + wx * h01) +
              wy * ((1.f - wx) * h10 + wx * h11);

    float s = l + h;
    if (sump_bf)
      sump_bf[((size_t)(b * CC + c)) * SPITCH + (y + 1) * 130 + (x + 1)] =
          f2bf(s);
    if (sum_f32)
      sum_f32[((size_t)(b * CC + c)) * (LHH * LWW) + y * LWW + x] = s;
    hmean += h;
    lmean += l;
    hmax = fmaxf(hmax, h);
    lmax = fmaxf(lmax, l);
  }
  int p = (b * 4) * (LHH * LWW) + y * LWW + x;
  gate_in[p] = hmean * (1.0f / CC);
  gate_in[p + LHH * LWW] = lmean * (1.0f / CC);
  gate_in[p + 2 * LHH * LWW] = hmax;
  gate_in[p + 3 * LHH * LWW] = lmax;
}

// ---------------------------------------------------------------------------
// K3: gate conv 4->1 3x3 + sigmoid
// ---------------------------------------------------------------------------
__global__ __launch_bounds__(256) void gate_kernel(
    const float* __restrict__ gate_in, const float* __restrict__ wg,
    float* __restrict__ gates) {
  int t = blockIdx.x * blockDim.x + threadIdx.x;
  if (t >= BB * LHH * LWW) return;
  int x = t & 127;
  int y = (t >> 7) & 127;
  int b = t >> 14;
  float acc = 0.f;
#pragma unroll
  for (int ic = 0; ic < 4; ++ic) {
    const float* img = gate_in + ((size_t)(b * 4 + ic)) * (LHH * LWW);
    const float* wc = wg + ic * 9;
#pragma unroll
    for (int dy = 0; dy < 3; ++dy) {
      int yy = y + dy - 1;
      if (yy < 0 || yy >= LHH) continue;
#pragma unroll
      for (int dx = 0; dx < 3; ++dx) {
        int xx = x + dx - 1;
        if (xx < 0 || xx >= LWW) continue;
        acc = fmaf(img[yy * LWW + xx], wc[dy * 3 + dx], acc);
      }
    }
  }
  gates[t] = 1.0f / (1.0f + expf(-acc));
}

// ---------------------------------------------------------------------------
// prep: B_t[oc][k] bf16, k = (dy*3+dx)*64 + ci, row stride BTS (pad zeroed)
// ---------------------------------------------------------------------------
__global__ __launch_bounds__(256) void prep_bt_kernel(
    const float* __restrict__ wflow, unsigned short* __restrict__ bt) {
  int t = blockIdx.x * blockDim.x + threadIdx.x;
  if (t >= 256 * BTS) return;
  int oc = t / BTS;
  int kd = t - oc * BTS;
  unsigned short v = 0;
  if (kd < 576) {
    int dydx = kd >> 6;
    int ci = kd & 63;
    v = f2bf(wflow[(oc * 64 + ci) * 9 + dydx]);
  }
  bt[t] = v;
}

// ---------------------------------------------------------------------------
// K4a: flow conv as implicit GEMM via MFMA bf16 16x16x32.
//  M-tile = 128 (one image row: fixed b,y, x=0..127), N-tile = 128.
//  K = 576 ordered (dydx, ci). A staged in LDS (reg-transposed), B from L2.
//  flow written bf16 NCHW: flow[b][oc][y*128+x].
// ---------------------------------------------------------------------------
__global__ __launch_bounds__(256) void flow_gemm_kernel(
    const unsigned short* __restrict__ sump, const unsigned short* __restrict__ bt,
    unsigned short* __restrict__ flow) {
  __shared__ unsigned short As[128 * ALDS];

  const int mt = blockIdx.x;       // 0..1023
  const int b = mt >> 7;
  const int y = mt & 127;
  const int n0 = blockIdx.y * 128; // 0 or 128

  const int tid = threadIdx.x;
  const int lane = tid & 63;
  const int wid = tid >> 6;
  const int wr = wid >> 1;         // wave row (0..1)  -> rows wr*64..+63
  const int wc = wid & 1;          // wave col (0..1)  -> cols wc*64..+63
  const int lr = lane & 15;
  const int lg = lane >> 4;

  // staging role: half = tid>>7 (ci 16-chunk), m = tid&127
  const int sm = tid & 127;
  const int shalf = tid >> 7;

  f32x4 acc[4][4];
#pragma unroll
  for (int i = 0; i < 4; ++i)
#pragma unroll
    for (int j = 0; j < 4; ++j) acc[i][j] = (f32x4){0.f, 0.f, 0.f, 0.f};

  const unsigned short* sb = sump + (size_t)(b * CC) * SPITCH;

  for (int dydx = 0; dydx < 9; ++dydx) {
    const int dy = dydx / 3;
    const int dx = dydx - dy * 3;
    const int row = y + dy;  // padded row 0..129
#pragma unroll
    for (int cc = 0; cc < 2; ++cc) {
      const int kbase = dydx * 64 + cc * 32;
      __syncthreads();
      // ---- stage A: As[m][0..31] = sum[b][cc*32+j][row][dx+m]
      {
        const unsigned short* sp =
            sb + (size_t)(cc * 32 + shalf * 16) * SPITCH + row * 130 + dx + sm;
        unsigned short v[16];
#pragma unroll
        for (int j = 0; j < 16; ++j) v[j] = sp[j * SPITCH];
        unsigned int pk[8];
#pragma unroll
        for (int j = 0; j < 8; ++j)
          pk[j] = (unsigned)v[2 * j] | ((unsigned)v[2 * j + 1] << 16);
        uint4v q0 = {pk[0], pk[1], pk[2], pk[3]};
        uint4v q1 = {pk[4], pk[5], pk[6], pk[7]};
        uint4v* dst = (uint4v*)&As[sm * ALDS + shalf * 16];
        dst[0] = q0;
        dst[1] = q1;
      }
      __syncthreads();
      // ---- fragments + MFMA
      short8v af[4], bf[4];
#pragma unroll
      for (int mf = 0; mf < 4; ++mf)
        af[mf] = *(const short8v*)&As[(wr * 64 + mf * 16 + lr) * ALDS + lg * 8];
#pragma unroll
      for (int nf = 0; nf < 4; ++nf)
        bf[nf] = *(const short8v*)&bt[(size_t)(n0 + wc * 64 + nf * 16 + lr) * BTS +
                                      kbase + lg * 8];
#pragma unroll
      for (int mf = 0; mf < 4; ++mf)
#pragma unroll
        for (int nf = 0; nf < 4; ++nf)
          acc[mf][nf] = __builtin_amdgcn_mfma_f32_16x16x32_bf16(
              af[mf], bf[nf], acc[mf][nf], 0, 0, 0);
    }
  }

  // ---- epilogue: D col(lane&15)=n, row=(lane>>4)*4+reg = x within tile
  unsigned short* fp = flow + (size_t)b * 256 * 16384;
#pragma unroll
  for (int mf = 0; mf < 4; ++mf) {
    const int mrow = wr * 64 + mf * 16 + lg * 4;  // x base (4 consecutive)
#pragma unroll
    for (int nf = 0; nf < 4; ++nf) {
      const int n = n0 + wc * 64 + nf * 16 + lr;
      unsigned int lo = (unsigned)f2bf(acc[mf][nf][0]) |
                        ((unsigned)f2bf(acc[mf][nf][1]) << 16);
      unsigned int hi = (unsigned)f2bf(acc[mf][nf][2]) |
                        ((unsigned)f2bf(acc[mf][nf][3]) << 16);
      uint2v st = {lo, hi};
      *(uint2v*)&fp[(size_t)n * 16384 + y * 128 + mrow] = st;
    }
  }
}

// ---------------------------------------------------------------------------
// zero-padded bilinear sample
// ---------------------------------------------------------------------------
__device__ __forceinline__ float bilin0(const float* __restrict__ img, int H,
                                        int W, float gx, float gy) {
  float x0f = floorf(gx), y0f = floorf(gy);
  float wx1 = gx - x0f, wy1 = gy - y0f;
  int x0 = (int)x0f, y0 = (int)y0f;
  float r = 0.f;
  if (x0 >= 0 && x0 < W && y0 >= 0 && y0 < H)
    r = fmaf(img[y0 * W + x0], (1.f - wx1) * (1.f - wy1), r);
  if (x0 + 1 >= 0 && x0 + 1 < W && y0 >= 0 && y0 < H)
    r = fmaf(img[y0 * W + x0 + 1], wx1 * (1.f - wy1), r);
  if (x0 >= 0 && x0 < W && y0 + 1 >= 0 && y0 + 1 < H)
    r = fmaf(img[(y0 + 1) * W + x0], (1.f - wx1) * wy1, r);
  if (x0 + 1 >= 0 && x0 + 1 < W && y0 + 1 >= 0 && y0 + 1 < H)
    r = fmaf(img[(y0 + 1) * W + x0 + 1], wx1 * wy1, r);
  return r;
}

// ---------------------------------------------------------------------------
// K4b: read 4 flow channels, warp high & low, blend with gate.
// ---------------------------------------------------------------------------
__global__ __launch_bounds__(256) void warp_combine_kernel(
    const unsigned short* __restrict__ flow, const float* __restrict__ low,
    const float* __restrict__ high, const float* __restrict__ gates,
    float* __restrict__ out) {
  int t = blockIdx.x * blockDim.x + threadIdx.x;
  if (t >= BB * CC * LHH * LWW) return;
  int m = t & 16383;               // y*128+x
  int c = (t >> 14) & 63;
  int b = t >> 20;
  int x = m & 127;
  int y = m >> 7;

  const unsigned short* fb = flow + (size_t)b * 256 * 16384;
  float a0 = bf2f(fb[(size_t)(2 * c) * 16384 + m]);
  float a1 = bf2f(fb[(size_t)(2 * c + 1) * 16384 + m]);
  float a2 = bf2f(fb[(size_t)(128 + 2 * c) * 16384 + m]);
  float a3 = bf2f(fb[(size_t)(129 + 2 * c) * 16384 + m]);

  float bx = -1.0f + x * (2.0f / 127.0f);
  float by = -1.0f + y * (2.0f / 127.0f);

  float gxh = (bx + a0 * (1.0f / 128.0f) + 1.0f) * 0.5f * (float)(HWW - 1);
  float gyh = (by + a1 * (1.0f / 128.0f) + 1.0f) * 0.5f * (float)(HHH - 1);
  float hwv =
      bilin0(high + ((size_t)(b * CC + c)) * (HHH * HWW), HHH, HWW, gxh, gyh);

  float gxl = (bx + a2 * (1.0f / 128.0f) + 1.0f) * 0.5f * (float)(LWW - 1);
  float gyl = (by + a3 * (1.0f / 128.0f) + 1.0f) * 0.5f * (float)(LHH - 1);
  float lwv =
      bilin0(low + ((size_t)(b * CC + c)) * (LHH * LWW), LHH, LWW, gxl, gyl);

  float g = gates[b * (LHH * LWW) + m];
  out[((size_t)(b * CC + c)) * (LHH * LWW) + m] = hwv * g + lwv * (1.0f - g);
}

// ---------------------------------------------------------------------------
// Fallback (round-1) fused kernel, used only if ws_size is too small.
// ---------------------------------------------------------------------------
__global__ __launch_bounds__(256) void flow_warp_combine_kernel(
    const float* __restrict__ sumbuf, const float* __restrict__ wflow,
    const float* __restrict__ low, const float* __restrict__ high,
    const float* __restrict__ gates, float* __restrict__ out) {
  const int c = blockIdx.x;
  const int tile = blockIdx.y;
  const int b = blockIdx.z;
  const int ty0 = (tile >> 3) * 16;
  const int tx0 = (tile & 7) * 16;
  const int tx = threadIdx.x, ty = threadIdx.y;
  const int tid = ty * 16 + tx;

  __shared__ float tileS[16][18][20];

  const float* w0 = wflow + (size_t)(2 * c) * 576;
  const float* w1 = wflow + (size_t)(2 * c + 1) * 576;
  const float* w2 = wflow + (size_t)(128 + 2 * c) * 576;
  const float* w3 = wflow + (size_t)(129 + 2 * c) * 576;

  float a0 = 0.f, a1 = 0.f, a2 = 0.f, a3 = 0.f;

  for (int cc = 0; cc < 4; ++cc) {
    const float* src = sumbuf + ((size_t)(b * CC + cc * 16)) * (LHH * LWW);
    for (int idx = tid; idx < 16 * 18 * 18; idx += 256) {
      int ci = idx / 324;
      int rem = idx - ci * 324;
      int r = rem / 18;
      int col = rem - r * 18;
      int gy = ty0 - 1 + r;
      int gx = tx0 - 1 + col;
      float v = 0.f;
      if (gy >= 0 && gy < LHH && gx >= 0 && gx < LWW)
        v = src[ci * (LHH * LWW) + gy * LWW + gx];
      tileS[ci][r][col] = v;
    }
    __syncthreads();
#pragma unroll 2
    for (int ci = 0; ci < 16; ++ci) {
      int wb = (cc * 16 + ci) * 9;
#pragma unroll
      for (int dy = 0; dy < 3; ++dy) {
#pragma unroll
        for (int dx = 0; dx < 3; ++dx) {
          float v = tileS[ci][ty + dy][tx + dx];
          int wi = wb + dy * 3 + dx;
          a0 = fmaf(v, w0[wi], a0);
          a1 = fmaf(v, w1[wi], a1);
          a2 = fmaf(v, w2[wi], a2);
          a3 = fmaf(v, w3[wi], a3);
        }
      }
    }
    __syncthreads();
  }

  const int y = ty0 + ty;
  const int x = tx0 + tx;
  float bx = -1.0f + x * (2.0f / 127.0f);
  float by = -1.0f + y * (2.0f / 127.0f);
  float gxh = (bx + a0 * (1.0f / 128.0f) + 1.0f) * 0.5f * (float)(HWW - 1);
  float gyh = (by + a1 * (1.0f / 128.0f) + 1.0f) * 0.5f * (float)(HHH - 1);
  float hwv =
      bilin0(high + ((size_t)(b * CC + c)) * (HHH * HWW), HHH, HWW, gxh, gyh);
  float gxl = (bx + a2 * (1.0f / 128.0f) + 1.0f) * 0.5f * (float)(LWW - 1);
  float gyl = (by + a3 * (1.0f / 128.0f) + 1.0f) * 0.5f * (float)(LHH - 1);
  float lwv =
      bilin0(low + ((size_t)(b * CC + c)) * (LHH * LWW), LHH, LWW, gxl, gyl);
  float g = gates[b * (LHH * LWW) + y * LWW + x];
  out[((size_t)(b * CC + c)) * (LHH * LWW) + y * LWW + x] =
      hwv * g + lwv * (1.0f - g);
}

// ---------------------------------------------------------------------------
extern "C" void kernel_launch(void* const* d_in, const int* in_sizes, int n_in,
                              void* d_out, int out_size, void* d_ws,
                              size_t ws_size, hipStream_t stream) {
  const float* low = (const float*)d_in[0];
  const float* high = (const float*)d_in[1];
  const float* w_conv_l = (const float*)d_in[2];
  const float* w_conv_h = (const float*)d_in[3];
  const float* w_flow = (const float*)d_in[4];
  const float* w_gate = (const float*)d_in[5];
  float* out = (float*)d_out;
  char* ws = (char*)d_ws;

  // layout (new path):
  const size_t OFF_HSMALL = 0;                       //  8,388,608
  const size_t OFF_SUMP = 8388608;                   // 17,305,600 (bf16 padded)
  const size_t OFF_GATEIN = 25694208;                //  2,097,152
  const size_t OFF_GATES = 27791360;                 //    524,288
  const size_t OFF_BT = 28315648;                    //    299,008
  const size_t OFF_FLOW = 28614656;                  // 67,108,864
  const size_t NEED = 95723520;

  if (ws_size >= NEED) {
    float* h_small = (float*)(ws + OFF_HSMALL);
    unsigned short* sump = (unsigned short*)(ws + OFF_SUMP);
    float* gate_in = (float*)(ws + OFF_GATEIN);
    float* gates = (float*)(ws + OFF_GATES);
    unsigned short* bt = (unsigned short*)(ws + OFF_BT);
    unsigned short* flow = (unsigned short*)(ws + OFF_FLOW);

    hipMemsetAsync(sump, 0, 17305600, stream);  // zero padding borders
    dw_high_kernel<<<(BB * CC * HHH * HWW + 255) / 256, 256, 0, stream>>>(
        high, w_conv_h, h_small);
    prep_bt_kernel<<<(256 * BTS + 255) / 256, 256, 0, stream>>>(w_flow, bt);
    fuse_sum_stats_kernel<<<(BB * LHH * LWW + 255) / 256, 256, 0, stream>>>(
        low, h_small, w_conv_l, sump, nullptr, gate_in);
    gate_kernel<<<(BB * LHH * LWW + 255) / 256, 256, 0, stream>>>(
        gate_in, w_gate, gates);
    dim3 gg(1024, 2);
    flow_gemm_kernel<<<gg, 256, 0, stream>>>(sump, bt, flow);
    warp_combine_kernel<<<(BB * CC * LHH * LWW + 255) / 256, 256, 0, stream>>>(
        flow, low, high, gates, out);
  } else {
    // fallback: round-1 path (ws >= 44.6 MB)
    float* h_small = (float*)(ws);
    float* sumbuf = (float*)(ws + 8388608);
    float* gate_in = (float*)(ws + 8388608 + 33554432);
    float* gates = (float*)(ws + 8388608 + 33554432 + 2097152);
    dw_high_kernel<<<(BB * CC * HHH * HWW + 255) / 256, 256, 0, stream>>>(
        high, w_conv_h, h_small);
    fuse_sum_stats_kernel<<<(BB * LHH * LWW + 255) / 256, 256, 0, stream>>>(
        low, h_small, w_conv_l, nullptr, sumbuf, gate_in);
    gate_kernel<<<(BB * LHH * LWW + 255) / 256, 256, 0, stream>>>(
        gate_in, w_gate, gates);
    dim3 g5(CC, 64, BB), b5(16, 16);
    flow_warp_combine_kernel<<<g5, b5, 0, stream>>>(sumbuf, w_flow, low, high,
                                                    gates, out);
  }
}

// Round 3
// 259.724 us; speedup vs baseline: 4.6481x; 1.2061x over previous
//
#include <hip/hip_runtime.h>
#include <math.h>

#define BB 8
#define CC 64
#define LHH 128
#define LWW 128
#define HHH 64
#define HWW 64

typedef __attribute__((ext_vector_type(8))) short short8v;
typedef __attribute__((ext_vector_type(4))) float f32x4;
typedef __attribute__((ext_vector_type(4))) unsigned int uint4v;
typedef __attribute__((ext_vector_type(2))) unsigned int uint2v;

#define BTS 584       // B_t row stride (shorts): 576 + 8 pad
#define SPITCH 16900  // 130*130 padded image (shorts)
#define ALDS 40       // As row stride in shorts (80 B)
#define FLS 136       // flowS row stride in shorts (272 B)

__device__ __forceinline__ unsigned short f2bf(float f) {
  unsigned u = __float_as_uint(f);
  unsigned r = (u + 0x7fffu + ((u >> 16) & 1u)) >> 16;
  return (unsigned short)r;
}
__device__ __forceinline__ float bf2f(unsigned short u) {
  return __uint_as_float(((unsigned)u) << 16);
}

// ---------------------------------------------------------------------------
// K1: depthwise 3x3 on high_feature -> h_small (B,C,64,64) fp32
// ---------------------------------------------------------------------------
__global__ __launch_bounds__(256) void dw_high_kernel(
    const float* __restrict__ hf, const float* __restrict__ w,
    float* __restrict__ out) {
  int t = blockIdx.x * blockDim.x + threadIdx.x;
  if (t >= BB * CC * HHH * HWW) return;
  int x = t & 63;
  int y = (t >> 6) & 63;
  int c = (t >> 12) & 63;
  int b = t >> 18;
  const float* img = hf + ((size_t)(b * CC + c)) * (HHH * HWW);
  const float* wc = w + c * 9;
  float acc = 0.f;
#pragma unroll
  for (int dy = 0; dy < 3; ++dy) {
    int yy = y + dy - 1;
    if (yy < 0 || yy >= HHH) continue;
#pragma unroll
    for (int dx = 0; dx < 3; ++dx) {
      int xx = x + dx - 1;
      if (xx < 0 || xx >= HWW) continue;
      acc = fmaf(img[yy * HWW + xx], wc[dy * 3 + dx], acc);
    }
  }
  out[t] = acc;
}

// ---------------------------------------------------------------------------
// K2a: grid (y, cgroup, b); block = 2 sub x 128 x. Each thread: 4 channels.
//   l = dw3x3(low), h = bilinear-up(h_small); sump bf16 write; partial stats.
// ---------------------------------------------------------------------------
__global__ __launch_bounds__(256) void fuse_sum_stats_kernel(
    const float* __restrict__ low, const float* __restrict__ hsm,
    const float* __restrict__ wl, unsigned short* __restrict__ sump,
    float* __restrict__ pstat) {
  const int x = threadIdx.x & 127;
  const int sub = threadIdx.x >> 7;
  const int y = blockIdx.x;
  const int cg = blockIdx.y;
  const int b = blockIdx.z;

  // jax.image.resize 64->128 half-pixel: src = (dst+0.5)*0.5 - 0.5
  float sy = 0.5f * y - 0.25f;
  float sx = 0.5f * x - 0.25f;
  float y0f = floorf(sy), x0f = floorf(sx);
  float wy = sy - y0f, wx = sx - x0f;
  int iy0 = (int)y0f, ix0 = (int)x0f;
  int iy0c = max(0, min(HHH - 1, iy0));
  int iy1c = max(0, min(HHH - 1, iy0 + 1));
  int ix0c = max(0, min(HWW - 1, ix0));
  int ix1c = max(0, min(HWW - 1, ix0 + 1));
  float w00 = (1.f - wy) * (1.f - wx), w01 = (1.f - wy) * wx;
  float w10 = wy * (1.f - wx), w11 = wy * wx;

  float hmean = 0.f, lmean = 0.f;
  float hmax = -3.402823466e+38f, lmax = -3.402823466e+38f;

#pragma unroll
  for (int j = 0; j < 4; ++j) {
    int c = cg * 8 + sub * 4 + j;
    const float* limg = low + ((size_t)(b * CC + c)) * (LHH * LWW);
    const float* wc = wl + c * 9;
    float l = 0.f;
#pragma unroll
    for (int dy = 0; dy < 3; ++dy) {
      int yy = y + dy - 1;
      if (yy < 0 || yy >= LHH) continue;
#pragma unroll
      for (int dx = 0; dx < 3; ++dx) {
        int xx = x + dx - 1;
        if (xx < 0 || xx >= LWW) continue;
        l = fmaf(limg[yy * LWW + xx], wc[dy * 3 + dx], l);
      }
    }
    const float* himg = hsm + ((size_t)(b * CC + c)) * (HHH * HWW);
    float h = w00 * himg[iy0c * HWW + ix0c] + w01 * himg[iy0c * HWW + ix1c] +
              w10 * himg[iy1c * HWW + ix0c] + w11 * himg[iy1c * HWW + ix1c];

    sump[((size_t)(b * CC + c)) * SPITCH + (y + 1) * 130 + (x + 1)] =
        f2bf(l + h);
    hmean += h;
    lmean += l;
    hmax = fmaxf(hmax, h);
    lmax = fmaxf(lmax, l);
  }

  __shared__ float sh[4][128];
  if (sub) {
    sh[0][x] = hmean;
    sh[1][x] = lmean;
    sh[2][x] = hmax;
    sh[3][x] = lmax;
  }
  __syncthreads();
  if (!sub) {
    hmean += sh[0][x];
    lmean += sh[1][x];
    hmax = fmaxf(hmax, sh[2][x]);
    lmax = fmaxf(lmax, sh[3][x]);
    size_t base = ((size_t)((b * 8 + cg) * 4)) * 16384 + y * 128 + x;
    pstat[base] = hmean;
    pstat[base + 16384] = lmean;
    pstat[base + 2 * 16384] = hmax;
    pstat[base + 3 * 16384] = lmax;
  }
}

// ---------------------------------------------------------------------------
// K2b: reduce 8 partial stat groups -> gate_in (B,4,H,W)
// ---------------------------------------------------------------------------
__global__ __launch_bounds__(256) void stat_reduce_kernel(
    const float* __restrict__ pstat, float* __restrict__ gate_in) {
  int t = blockIdx.x * blockDim.x + threadIdx.x;
  if (t >= BB * 16384) return;
  int m = t & 16383;
  int b = t >> 14;
  float hm = 0.f, lm = 0.f;
  float hx = -3.402823466e+38f, lx = -3.402823466e+38f;
#pragma unroll
  for (int cg = 0; cg < 8; ++cg) {
    size_t base = ((size_t)((b * 8 + cg) * 4)) * 16384 + m;
    hm += pstat[base];
    lm += pstat[base + 16384];
    hx = fmaxf(hx, pstat[base + 2 * 16384]);
    lx = fmaxf(lx, pstat[base + 3 * 16384]);
  }
  int p = b * 4 * 16384 + m;
  gate_in[p] = hm * (1.0f / CC);
  gate_in[p + 16384] = lm * (1.0f / CC);
  gate_in[p + 2 * 16384] = hx;
  gate_in[p + 3 * 16384] = lx;
}

// ---------------------------------------------------------------------------
// K3: gate conv 4->1 3x3 + sigmoid
// ---------------------------------------------------------------------------
__global__ __launch_bounds__(256) void gate_kernel(
    const float* __restrict__ gate_in, const float* __restrict__ wg,
    float* __restrict__ gates) {
  int t = blockIdx.x * blockDim.x + threadIdx.x;
  if (t >= BB * LHH * LWW) return;
  int x = t & 127;
  int y = (t >> 7) & 127;
  int b = t >> 14;
  float acc = 0.f;
#pragma unroll
  for (int ic = 0; ic < 4; ++ic) {
    const float* img = gate_in + ((size_t)(b * 4 + ic)) * (LHH * LWW);
    const float* wc = wg + ic * 9;
#pragma unroll
    for (int dy = 0; dy < 3; ++dy) {
      int yy = y + dy - 1;
      if (yy < 0 || yy >= LHH) continue;
#pragma unroll
      for (int dx = 0; dx < 3; ++dx) {
        int xx = x + dx - 1;
        if (xx < 0 || xx >= LWW) continue;
        acc = fmaf(img[yy * LWW + xx], wc[dy * 3 + dx], acc);
      }
    }
  }
  gates[t] = 1.0f / (1.0f + expf(-acc));
}

// ---------------------------------------------------------------------------
// prep: B_t[oc][k] bf16, k = (dy*3+dx)*64 + ci
// ---------------------------------------------------------------------------
__global__ __launch_bounds__(256) void prep_bt_kernel(
    const float* __restrict__ wflow, unsigned short* __restrict__ bt) {
  int t = blockIdx.x * blockDim.x + threadIdx.x;
  if (t >= 256 * BTS) return;
  int oc = t / BTS;
  int kd = t - oc * BTS;
  unsigned short v = 0;
  if (kd < 576) {
    int dydx = kd >> 6;
    int ci = kd & 63;
    v = f2bf(wflow[(oc * 64 + ci) * 9 + dydx]);
  }
  bt[t] = v;
}

// ---------------------------------------------------------------------------
// zero-padded bilinear sample
// ---------------------------------------------------------------------------
__device__ __forceinline__ float bilin0(const float* __restrict__ img, int H,
                                        int W, float gx, float gy) {
  float x0f = floorf(gx), y0f = floorf(gy);
  float wx1 = gx - x0f, wy1 = gy - y0f;
  int x0 = (int)x0f, y0 = (int)y0f;
  float r = 0.f;
  if (x0 >= 0 && x0 < W && y0 >= 0 && y0 < H)
    r = fmaf(img[y0 * W + x0], (1.f - wx1) * (1.f - wy1), r);
  if (x0 + 1 >= 0 && x0 + 1 < W && y0 >= 0 && y0 < H)
    r = fmaf(img[y0 * W + x0 + 1], wx1 * (1.f - wy1), r);
  if (x0 >= 0 && x0 < W && y0 + 1 >= 0 && y0 + 1 < H)
    r = fmaf(img[(y0 + 1) * W + x0], (1.f - wx1) * wy1, r);
  if (x0 + 1 >= 0 && x0 + 1 < W && y0 + 1 >= 0 && y0 + 1 < H)
    r = fmaf(img[(y0 + 1) * W + x0 + 1], wx1 * wy1, r);
  return r;
}

// ---------------------------------------------------------------------------
// K4: fused flow-GEMM (M=128 pixels of one row, N=256 out-ch, K=576 bf16
//     MFMA) + LDS flow tile + bilinear warps + gated blend -> out.
//  8 waves: wr=wid>>2 (m-half), wc=wid&3 (n-quarter); acc 4x4 frags/wave.
// ---------------------------------------------------------------------------
__global__ __launch_bounds__(512, 4) void flow_gemm_combine_kernel(
    const unsigned short* __restrict__ sump,
    const unsigned short* __restrict__ bt, const float* __restrict__ low,
    const float* __restrict__ high, const float* __restrict__ gates,
    float* __restrict__ out) {
  __shared__ unsigned short As[128 * ALDS];    // 10240 B
  __shared__ unsigned short flowS[256 * FLS];  // 69632 B

  const int y = blockIdx.x;
  const int b = blockIdx.y;
  const int tid = threadIdx.x;
  const int lane = tid & 63;
  const int wid = tid >> 6;
  const int wr = wid >> 2;  // 0..1: m-half (rows wr*64..+63)
  const int wc = wid & 3;   // 0..3: n-quarter (cols wc*64..+63)
  const int lr = lane & 15;
  const int lg = lane >> 4;
  const int sm = tid & 127;  // staging: pixel index
  const int q = tid >> 7;    // staging: ci-octet / combine: c-group

  f32x4 acc[4][4];
#pragma unroll
  for (int i = 0; i < 4; ++i)
#pragma unroll
    for (int j = 0; j < 4; ++j) acc[i][j] = (f32x4){0.f, 0.f, 0.f, 0.f};

  const unsigned short* sb = sump + (size_t)(b * CC) * SPITCH;

  for (int dydx = 0; dydx < 9; ++dydx) {
    const int dy = dydx / 3;
    const int dx = dydx - dy * 3;
    const int row = y + dy;  // padded row 0..129
#pragma unroll
    for (int cc = 0; cc < 2; ++cc) {
      const int kbase = dydx * 64 + cc * 32;
      __syncthreads();
      {  // stage A: As[m][k2] = sum[b][cc*32+k2][row][dx+m], k2=q*8..q*8+7
        const unsigned short* sp =
            sb + (size_t)(cc * 32 + q * 8) * SPITCH + row * 130 + dx + sm;
        unsigned short v[8];
#pragma unroll
        for (int j = 0; j < 8; ++j) v[j] = sp[j * SPITCH];
        unsigned int pk[4];
#pragma unroll
        for (int j = 0; j < 4; ++j)
          pk[j] = (unsigned)v[2 * j] | ((unsigned)v[2 * j + 1] << 16);
        *(uint4v*)&As[sm * ALDS + q * 8] = (uint4v){pk[0], pk[1], pk[2], pk[3]};
      }
      __syncthreads();
      short8v af[4], bfr[4];
#pragma unroll
      for (int mf = 0; mf < 4; ++mf)
        af[mf] = *(const short8v*)&As[(wr * 64 + mf * 16 + lr) * ALDS + lg * 8];
#pragma unroll
      for (int nf = 0; nf < 4; ++nf)
        bfr[nf] = *(const short8v*)&bt[(size_t)(wc * 64 + nf * 16 + lr) * BTS +
                                       kbase + lg * 8];
#pragma unroll
      for (int mf = 0; mf < 4; ++mf)
#pragma unroll
        for (int nf = 0; nf < 4; ++nf)
          acc[mf][nf] = __builtin_amdgcn_mfma_f32_16x16x32_bf16(
              af[mf], bfr[nf], acc[mf][nf], 0, 0, 0);
    }
  }

  __syncthreads();
  // dump accumulators to flowS[n][m] (bf16). D: col=lane&15 -> n, rows
  // (lane>>4)*4+reg -> m (4 consecutive).
#pragma unroll
  for (int mf = 0; mf < 4; ++mf) {
    const int m0 = wr * 64 + mf * 16 + lg * 4;
#pragma unroll
    for (int nf = 0; nf < 4; ++nf) {
      const int n = wc * 64 + nf * 16 + lr;
      unsigned int lo = (unsigned)f2bf(acc[mf][nf][0]) |
                        ((unsigned)f2bf(acc[mf][nf][1]) << 16);
      unsigned int hi = (unsigned)f2bf(acc[mf][nf][2]) |
                        ((unsigned)f2bf(acc[mf][nf][3]) << 16);
      *(uint2v*)&flowS[n * FLS + m0] = (uint2v){lo, hi};
    }
  }
  __syncthreads();

  // combine: thread (q, x=sm) handles c = q*16 .. q*16+15 at pixel (y, x)
  const int x = sm;
  const float g = gates[b * 16384 + y * 128 + x];
  const float bx = -1.0f + x * (2.0f / 127.0f);
  const float by = -1.0f + y * (2.0f / 127.0f);
  const float* lowb = low + (size_t)b * CC * (LHH * LWW);
  const float* highb = high + (size_t)b * CC * (HHH * HWW);
  float* outb = out + (size_t)b * CC * (LHH * LWW);

  for (int ci = 0; ci < 16; ++ci) {
    const int c = q * 16 + ci;
    float a0 = bf2f(flowS[(2 * c) * FLS + x]);
    float a1 = bf2f(flowS[(2 * c + 1) * FLS + x]);
    float a2 = bf2f(flowS[(128 + 2 * c) * FLS + x]);
    float a3 = bf2f(flowS[(129 + 2 * c) * FLS + x]);

    float gxh = (bx + a0 * (1.0f / 128.0f) + 1.0f) * 0.5f * (float)(HWW - 1);
    float gyh = (by + a1 * (1.0f / 128.0f) + 1.0f) * 0.5f * (float)(HHH - 1);
    float hwv = bilin0(highb + (size_t)c * (HHH * HWW), HHH, HWW, gxh, gyh);

    float gxl = (bx + a2 * (1.0f / 128.0f) + 1.0f) * 0.5f * (float)(LWW - 1);
    float gyl = (by + a3 * (1.0f / 128.0f) + 1.0f) * 0.5f * (float)(LHH - 1);
    float lwv = bilin0(lowb + (size_t)c * (LHH * LWW), LHH, LWW, gxl, gyl);

    outb[(size_t)c * (LHH * LWW) + y * 128 + x] = hwv * g + lwv * (1.0f - g);
  }
}

// ---------------------------------------------------------------------------
extern "C" void kernel_launch(void* const* d_in, const int* in_sizes, int n_in,
                              void* d_out, int out_size, void* d_ws,
                              size_t ws_size, hipStream_t stream) {
  const float* low = (const float*)d_in[0];
  const float* high = (const float*)d_in[1];
  const float* w_conv_l = (const float*)d_in[2];
  const float* w_conv_h = (const float*)d_in[3];
  const float* w_flow = (const float*)d_in[4];
  const float* w_gate = (const float*)d_in[5];
  float* out = (float*)d_out;
  char* ws = (char*)d_ws;

  const size_t OFF_HSMALL = 0;              //  8,388,608
  const size_t OFF_SUMP = 8388608;          // 17,305,600 (bf16 padded)
  const size_t OFF_GATEIN = 25694208;       //  2,097,152
  const size_t OFF_GATES = 27791360;        //    524,288
  const size_t OFF_BT = 28315648;           //    299,008
  const size_t OFF_PSTAT = 28614656;        // 16,777,216

  float* h_small = (float*)(ws + OFF_HSMALL);
  unsigned short* sump = (unsigned short*)(ws + OFF_SUMP);
  float* gate_in = (float*)(ws + OFF_GATEIN);
  float* gates = (float*)(ws + OFF_GATES);
  unsigned short* bt = (unsigned short*)(ws + OFF_BT);
  float* pstat = (float*)(ws + OFF_PSTAT);

  hipMemsetAsync(sump, 0, 17305600, stream);  // zero padded borders
  dw_high_kernel<<<(BB * CC * HHH * HWW + 255) / 256, 256, 0, stream>>>(
      high, w_conv_h, h_small);
  prep_bt_kernel<<<(256 * BTS + 255) / 256, 256, 0, stream>>>(w_flow, bt);
  fuse_sum_stats_kernel<<<dim3(128, 8, BB), 256, 0, stream>>>(
      low, h_small, w_conv_l, sump, pstat);
  stat_reduce_kernel<<<(BB * 16384 + 255) / 256, 256, 0, stream>>>(pstat,
                                                                   gate_in);
  gate_kernel<<<(BB * LHH * LWW + 255) / 256, 256, 0, stream>>>(gate_in,
                                                                w_gate, gates);
  flow_gemm_combine_kernel<<<dim3(128, BB), 512, 0, stream>>>(
      sump, bt, low, high, gates, out);
}

// Round 4
// 212.773 us; speedup vs baseline: 5.6738x; 1.2207x over previous
//
#include <hip/hip_runtime.h>
#include <math.h>

#define BB 8
#define CC 64
#define LHH 128
#define LWW 128
#define HHH 64
#define HWW 64

typedef __attribute__((ext_vector_type(8))) short short8v;
typedef __attribute__((ext_vector_type(4))) float f32x4;
typedef __attribute__((ext_vector_type(2))) unsigned int uint2v;

#define BTS 584   // B_t row stride (shorts): 576 + 8 pad
#define FLS 136   // flowS row stride (shorts)
// sump layout: [b][row:130][px:130][ch:64] bf16; row = 8320 shorts = 16640 B
#define SROWB 16640            // bytes per row
#define SIMGB (130 * SROWB)    // bytes per image (2,163,200)

__device__ __forceinline__ unsigned short f2bf(float f) {
  unsigned u = __float_as_uint(f);
  unsigned r = (u + 0x7fffu + ((u >> 16) & 1u)) >> 16;
  return (unsigned short)r;
}
__device__ __forceinline__ float bf2f(unsigned short u) {
  return __uint_as_float(((unsigned)u) << 16);
}

// ---------------------------------------------------------------------------
// K1: depthwise 3x3 on high_feature -> h_small (B,C,64,64) fp32
// ---------------------------------------------------------------------------
__global__ __launch_bounds__(256) void dw_high_kernel(
    const float* __restrict__ hf, const float* __restrict__ w,
    float* __restrict__ out) {
  int t = blockIdx.x * blockDim.x + threadIdx.x;
  if (t >= BB * CC * HHH * HWW) return;
  int x = t & 63;
  int y = (t >> 6) & 63;
  int c = (t >> 12) & 63;
  int b = t >> 18;
  const float* img = hf + ((size_t)(b * CC + c)) * (HHH * HWW);
  const float* wc = w + c * 9;
  float acc = 0.f;
#pragma unroll
  for (int dy = 0; dy < 3; ++dy) {
    int yy = y + dy - 1;
    if (yy < 0 || yy >= HHH) continue;
#pragma unroll
    for (int dx = 0; dx < 3; ++dx) {
      int xx = x + dx - 1;
      if (xx < 0 || xx >= HWW) continue;
      acc = fmaf(img[yy * HWW + xx], wc[dy * 3 + dx], acc);
    }
  }
  out[t] = acc;
}

// ---------------------------------------------------------------------------
// K2: grid flat 1024 (b = bid&7 -> XCD-affine, y = bid>>3), block 512.
//  Thread (x = tid&127, q = tid>>7) computes 16 channels c = q*16+j:
//  l = dw3x3(low), h = bilinear-up(h_small). Writes sump row (y+1) in
//  [px][ch] bf16 layout via LDS transpose; reduces gate stats in-block.
// ---------------------------------------------------------------------------
__global__ __launch_bounds__(512) void fuse_sum_stats_kernel(
    const float* __restrict__ low, const float* __restrict__ hsm,
    const float* __restrict__ wl, unsigned short* __restrict__ sump,
    float* __restrict__ gate_in) {
  __shared__ unsigned short sumS[128 * 64];  // 16 KB, XOR-swizzled
  __shared__ float sh[4][4][128];            // 8 KB stats

  const int bid = blockIdx.x;
  const int b = bid & 7;
  const int y = bid >> 3;
  const int tid = threadIdx.x;
  const int x = tid & 127;
  const int q = tid >> 7;

  // bilinear-up coords (64 -> 128, half-pixel)
  float sy = 0.5f * y - 0.25f;
  float sx = 0.5f * x - 0.25f;
  float y0f = floorf(sy), x0f = floorf(sx);
  float wy = sy - y0f, wx = sx - x0f;
  int iy0 = (int)y0f, ix0 = (int)x0f;
  int iy0c = max(0, min(HHH - 1, iy0));
  int iy1c = max(0, min(HHH - 1, iy0 + 1));
  int ix0c = max(0, min(HWW - 1, ix0));
  int ix1c = max(0, min(HWW - 1, ix0 + 1));
  float w00 = (1.f - wy) * (1.f - wx), w01 = (1.f - wy) * wx;
  float w10 = wy * (1.f - wx), w11 = wy * wx;

  float hmean = 0.f, lmean = 0.f;
  float hmax = -3.402823466e+38f, lmax = -3.402823466e+38f;

  unsigned short sv[16];
#pragma unroll 4
  for (int j = 0; j < 16; ++j) {
    const int c = q * 16 + j;
    const float* limg = low + ((size_t)(b * CC + c)) * (LHH * LWW);
    const float* wc = wl + c * 9;
    float l = 0.f;
#pragma unroll
    for (int dy = 0; dy < 3; ++dy) {
      int yy = y + dy - 1;
      if (yy < 0 || yy >= LHH) continue;
#pragma unroll
      for (int dx = 0; dx < 3; ++dx) {
        int xx = x + dx - 1;
        if (xx < 0 || xx >= LWW) continue;
        l = fmaf(limg[yy * LWW + xx], wc[dy * 3 + dx], l);
      }
    }
    const float* himg = hsm + ((size_t)(b * CC + c)) * (HHH * HWW);
    float h = w00 * himg[iy0c * HWW + ix0c] + w01 * himg[iy0c * HWW + ix1c] +
              w10 * himg[iy1c * HWW + ix0c] + w11 * himg[iy1c * HWW + ix1c];
    sv[j] = f2bf(l + h);
    hmean += h;
    lmean += l;
    hmax = fmaxf(hmax, h);
    lmax = fmaxf(lmax, l);
  }

  // pack 16 shorts -> two b128 LDS writes at swizzled addr
  {
    unsigned int pk[8];
#pragma unroll
    for (int j = 0; j < 8; ++j)
      pk[j] = (unsigned)sv[2 * j] | ((unsigned)sv[2 * j + 1] << 16);
    const int u0 = (x * 128 + q * 32) ^ ((x & 7) << 4);
    const int u1 = (x * 128 + q * 32 + 16) ^ ((x & 7) << 4);
    *(short8v*)((char*)sumS + u0) =
        *(short8v*)&pk[0];
    *(short8v*)((char*)sumS + u1) =
        *(short8v*)&pk[4];
  }
  sh[0][q][x] = hmean;
  sh[1][q][x] = lmean;
  sh[2][q][x] = hmax;
  sh[3][q][x] = lmax;
  __syncthreads();

  // coalesced write-out: 16 KB -> global row (y+1), px 1..128
  {
    char* dst = (char*)sump + (size_t)b * SIMGB + (size_t)(y + 1) * SROWB + 128;
#pragma unroll
    for (int pass = 0; pass < 2; ++pass) {
      int o = (tid + pass * 512) * 16;
      int L = o ^ (((o >> 7) & 7) << 4);
      *(short8v*)(dst + o) = *(const short8v*)((const char*)sumS + L);
    }
  }
  // stats reduce: tid -> (s = tid>>7, x)
  {
    const int s = q;
    float v0 = sh[s][0][x], v1 = sh[s][1][x], v2 = sh[s][2][x], v3 = sh[s][3][x];
    float r;
    if (s < 2)
      r = (v0 + v1 + v2 + v3) * (1.0f / CC);
    else
      r = fmaxf(fmaxf(v0, v1), fmaxf(v2, v3));
    gate_in[((size_t)(b * 4 + s)) * 16384 + y * 128 + x] = r;
  }
}

// ---------------------------------------------------------------------------
// K3: gate conv 4->1 3x3 + sigmoid
// ---------------------------------------------------------------------------
__global__ __launch_bounds__(256) void gate_kernel(
    const float* __restrict__ gate_in, const float* __restrict__ wg,
    float* __restrict__ gates) {
  int t = blockIdx.x * blockDim.x + threadIdx.x;
  if (t >= BB * LHH * LWW) return;
  int x = t & 127;
  int y = (t >> 7) & 127;
  int b = t >> 14;
  float acc = 0.f;
#pragma unroll
  for (int ic = 0; ic < 4; ++ic) {
    const float* img = gate_in + ((size_t)(b * 4 + ic)) * (LHH * LWW);
    const float* wc = wg + ic * 9;
#pragma unroll
    for (int dy = 0; dy < 3; ++dy) {
      int yy = y + dy - 1;
      if (yy < 0 || yy >= LHH) continue;
#pragma unroll
      for (int dx = 0; dx < 3; ++dx) {
        int xx = x + dx - 1;
        if (xx < 0 || xx >= LWW) continue;
        acc = fmaf(img[yy * LWW + xx], wc[dy * 3 + dx], acc);
      }
    }
  }
  gates[t] = 1.0f / (1.0f + expf(-acc));
}

// ---------------------------------------------------------------------------
// prep: B_t[oc][k] bf16, k = (dy*3+dx)*64 + ci
// ---------------------------------------------------------------------------
__global__ __launch_bounds__(256) void prep_bt_kernel(
    const float* __restrict__ wflow, unsigned short* __restrict__ bt) {
  int t = blockIdx.x * blockDim.x + threadIdx.x;
  if (t >= 256 * BTS) return;
  int oc = t / BTS;
  int kd = t - oc * BTS;
  unsigned short v = 0;
  if (kd < 576) {
    int dydx = kd >> 6;
    int ci = kd & 63;
    v = f2bf(wflow[(oc * 64 + ci) * 9 + dydx]);
  }
  bt[t] = v;
}

// ---------------------------------------------------------------------------
// zero-padded bilinear sample
// ---------------------------------------------------------------------------
__device__ __forceinline__ float bilin0(const float* __restrict__ img, int H,
                                        int W, float gx, float gy) {
  float x0f = floorf(gx), y0f = floorf(gy);
  float wx1 = gx - x0f, wy1 = gy - y0f;
  int x0 = (int)x0f, y0 = (int)y0f;
  float r = 0.f;
  if (x0 >= 0 && x0 < W && y0 >= 0 && y0 < H)
    r = fmaf(img[y0 * W + x0], (1.f - wx1) * (1.f - wy1), r);
  if (x0 + 1 >= 0 && x0 + 1 < W && y0 >= 0 && y0 < H)
    r = fmaf(img[y0 * W + x0 + 1], wx1 * (1.f - wy1), r);
  if (x0 >= 0 && x0 < W && y0 + 1 >= 0 && y0 + 1 < H)
    r = fmaf(img[(y0 + 1) * W + x0], (1.f - wx1) * wy1, r);
  if (x0 + 1 >= 0 && x0 + 1 < W && y0 + 1 >= 0 && y0 + 1 < H)
    r = fmaf(img[(y0 + 1) * W + x0 + 1], wx1 * wy1, r);
  return r;
}

// ---------------------------------------------------------------------------
// K4: fused flow-GEMM + warp + blend. grid flat 1024 (b = bid&7).
//  Stage rows y..y+2 of sump ([px][ch] bf16, 49920 B) into LDS ONCE
//  (XOR-swizzled), then barrier-free K-loop: 9 dydx x 2 cc x 16 MFMA.
//  Accumulators -> flowS (LDS union) -> bilinear warps -> out.
// ---------------------------------------------------------------------------
__global__ __launch_bounds__(512, 4) void flow_gemm_combine_kernel(
    const unsigned short* __restrict__ sump,
    const unsigned short* __restrict__ bt, const float* __restrict__ low,
    const float* __restrict__ high, const float* __restrict__ gates,
    float* __restrict__ out) {
  __shared__ unsigned short ldsU[256 * FLS];  // 69632 B union:
  // phase 1: rowCache [3][130][64] bf16 XOR-swizzled (49920 B)
  // phase 2: flowS [256][FLS]

  const int bid = blockIdx.x;
  const int b = bid & 7;
  const int y = bid >> 3;
  const int tid = threadIdx.x;
  const int lane = tid & 63;
  const int wid = tid >> 6;
  const int wr = wid >> 2;  // m-half
  const int wc = wid & 3;   // n-quarter
  const int lr = lane & 15;
  const int lg = lane >> 4;

  // ---- stage rows y..y+2 (contiguous 49920 B in global)
  {
    const char* src = (const char*)sump + (size_t)b * SIMGB + (size_t)y * SROWB;
    char* dstb = (char*)ldsU;
    for (int o = tid * 16; o < 3 * SROWB; o += 512 * 16) {
      int L = o ^ (((o >> 7) & 7) << 4);
      *(short8v*)(dstb + L) = *(const short8v*)(src + o);
    }
  }
  __syncthreads();

  f32x4 acc[4][4];
#pragma unroll
  for (int i = 0; i < 4; ++i)
#pragma unroll
    for (int j = 0; j < 4; ++j) acc[i][j] = (f32x4){0.f, 0.f, 0.f, 0.f};

  const char* rc = (const char*)ldsU;
  for (int dydx = 0; dydx < 9; ++dydx) {
    const int dy = dydx / 3;
    const int dx = dydx - dy * 3;
#pragma unroll
    for (int cc = 0; cc < 2; ++cc) {
      short8v af[4], bfr[4];
#pragma unroll
      for (int mf = 0; mf < 4; ++mf) {
        const int p = dy * 130 + dx + wr * 64 + mf * 16 + lr;
        const int fa = (p * 128 + cc * 64 + lg * 16) ^ ((p & 7) << 4);
        af[mf] = *(const short8v*)(rc + fa);
      }
#pragma unroll
      for (int nf = 0; nf < 4; ++nf)
        bfr[nf] = *(const short8v*)&bt[(size_t)(wc * 64 + nf * 16 + lr) * BTS +
                                       dydx * 64 + cc * 32 + lg * 8];
#pragma unroll
      for (int mf = 0; mf < 4; ++mf)
#pragma unroll
        for (int nf = 0; nf < 4; ++nf)
          acc[mf][nf] = __builtin_amdgcn_mfma_f32_16x16x32_bf16(
              af[mf], bfr[nf], acc[mf][nf], 0, 0, 0);
    }
  }

  __syncthreads();  // rowCache fully consumed; reuse LDS as flowS
  // dump acc -> flowS[n][m] bf16. D: col(lane&15)=n, row=(lane>>4)*4+reg=m.
#pragma unroll
  for (int mf = 0; mf < 4; ++mf) {
    const int m0 = wr * 64 + mf * 16 + lg * 4;
#pragma unroll
    for (int nf = 0; nf < 4; ++nf) {
      const int n = wc * 64 + nf * 16 + lr;
      unsigned int lo = (unsigned)f2bf(acc[mf][nf][0]) |
                        ((unsigned)f2bf(acc[mf][nf][1]) << 16);
      unsigned int hi = (unsigned)f2bf(acc[mf][nf][2]) |
                        ((unsigned)f2bf(acc[mf][nf][3]) << 16);
      *(uint2v*)&ldsU[n * FLS + m0] = (uint2v){lo, hi};
    }
  }
  __syncthreads();

  // combine: thread (q = tid>>7, x = tid&127) handles c = q*16..q*16+15
  const int x = tid & 127;
  const int q = tid >> 7;
  const float g = gates[b * 16384 + y * 128 + x];
  const float bx = -1.0f + x * (2.0f / 127.0f);
  const float by = -1.0f + y * (2.0f / 127.0f);
  const float* lowb = low + (size_t)b * CC * (LHH * LWW);
  const float* highb = high + (size_t)b * CC * (HHH * HWW);
  float* outb = out + (size_t)b * CC * (LHH * LWW);

  for (int ci = 0; ci < 16; ++ci) {
    const int c = q * 16 + ci;
    float a0 = bf2f(ldsU[(2 * c) * FLS + x]);
    float a1 = bf2f(ldsU[(2 * c + 1) * FLS + x]);
    float a2 = bf2f(ldsU[(128 + 2 * c) * FLS + x]);
    float a3 = bf2f(ldsU[(129 + 2 * c) * FLS + x]);

    float gxh = (bx + a0 * (1.0f / 128.0f) + 1.0f) * 0.5f * (float)(HWW - 1);
    float gyh = (by + a1 * (1.0f / 128.0f) + 1.0f) * 0.5f * (float)(HHH - 1);
    float hwv = bilin0(highb + (size_t)c * (HHH * HWW), HHH, HWW, gxh, gyh);

    float gxl = (bx + a2 * (1.0f / 128.0f) + 1.0f) * 0.5f * (float)(LWW - 1);
    float gyl = (by + a3 * (1.0f / 128.0f) + 1.0f) * 0.5f * (float)(LHH - 1);
    float lwv = bilin0(lowb + (size_t)c * (LHH * LWW), LHH, LWW, gxl, gyl);

    outb[(size_t)c * (LHH * LWW) + y * 128 + x] = hwv * g + lwv * (1.0f - g);
  }
}

// ---------------------------------------------------------------------------
extern "C" void kernel_launch(void* const* d_in, const int* in_sizes, int n_in,
                              void* d_out, int out_size, void* d_ws,
                              size_t ws_size, hipStream_t stream) {
  const float* low = (const float*)d_in[0];
  const float* high = (const float*)d_in[1];
  const float* w_conv_l = (const float*)d_in[2];
  const float* w_conv_h = (const float*)d_in[3];
  const float* w_flow = (const float*)d_in[4];
  const float* w_gate = (const float*)d_in[5];
  float* out = (float*)d_out;
  char* ws = (char*)d_ws;

  const size_t OFF_HSMALL = 0;         //  8,388,608
  const size_t OFF_SUMP = 8388608;     // 17,305,600 (bf16 [b][row][px][ch])
  const size_t OFF_GATEIN = 25694208;  //  2,097,152
  const size_t OFF_GATES = 27791360;   //    524,288
  const size_t OFF_BT = 28315648;      //    299,008

  float* h_small = (float*)(ws + OFF_HSMALL);
  unsigned short* sump = (unsigned short*)(ws + OFF_SUMP);
  float* gate_in = (float*)(ws + OFF_GATEIN);
  float* gates = (float*)(ws + OFF_GATES);
  unsigned short* bt = (unsigned short*)(ws + OFF_BT);

  hipMemsetAsync(sump, 0, 17305600, stream);  // zero padded borders
  dw_high_kernel<<<(BB * CC * HHH * HWW + 255) / 256, 256, 0, stream>>>(
      high, w_conv_h, h_small);
  prep_bt_kernel<<<(256 * BTS + 255) / 256, 256, 0, stream>>>(w_flow, bt);
  fuse_sum_stats_kernel<<<1024, 512, 0, stream>>>(low, h_small, w_conv_l, sump,
                                                  gate_in);
  gate_kernel<<<(BB * LHH * LWW + 255) / 256, 256, 0, stream>>>(gate_in,
                                                                w_gate, gates);
  flow_gemm_combine_kernel<<<1024, 512, 0, stream>>>(sump, bt, low, high,
                                                     gates, out);
}

// Round 5
// 205.442 us; speedup vs baseline: 5.8762x; 1.0357x over previous
//
#include <hip/hip_runtime.h>
#include <math.h>

#define BB 8
#define CC 64
#define LHH 128
#define LWW 128
#define HHH 64
#define HWW 64

typedef __attribute__((ext_vector_type(8))) short short8v;
typedef __attribute__((ext_vector_type(4))) float f32x4;

#define BTS 584   // B_t row stride (shorts): 576 + 8 pad
// sump layout: [b][row:130][px:130][ch:64] bf16; row = 8320 shorts = 16640 B
#define SROWB 16640          // bytes per row
#define SIMGB (130 * SROWB)  // bytes per image (2,163,200)

__device__ __forceinline__ unsigned short f2bf(float f) {
  unsigned u = __float_as_uint(f);
  unsigned r = (u + 0x7fffu + ((u >> 16) & 1u)) >> 16;
  return (unsigned short)r;
}

// ---------------------------------------------------------------------------
// K0: zero the padded borders of sump (rows 0,129 full; cols 0,129 rows 1..128)
//  528 KB instead of 17 MB memset.
// ---------------------------------------------------------------------------
__global__ __launch_bounds__(256) void zero_border_kernel(
    unsigned short* __restrict__ sump) {
  int t = blockIdx.x * blockDim.x + threadIdx.x;
  if (t >= 8 * 4128) return;
  int b = t / 4128;
  int r = t - b * 4128;
  char* base = (char*)sump + (size_t)b * SIMGB;
  char* dst;
  if (r < 2080) {  // rows 0 and 129: 1040 chunks of 16B each
    int row = (r < 1040) ? 0 : 129;
    int o = (r % 1040) * 16;
    dst = base + (size_t)row * SROWB + o;
  } else {  // rows 1..128, px 0 and 129: 128B each = 8 chunks
    int r2 = r - 2080;           // 0..2047
    int row = 1 + (r2 >> 4);     // 16 chunks per row
    int idx = r2 & 15;
    int side = idx >> 3;         // 0 -> px0, 1 -> px129
    int o = (idx & 7) * 16;
    dst = base + (size_t)row * SROWB + side * (129 * 128) + o;
  }
  *(short8v*)dst = (short8v){0, 0, 0, 0, 0, 0, 0, 0};
}

// ---------------------------------------------------------------------------
// K1: depthwise 3x3 on high_feature -> h_small (B,C,64,64) fp32
// ---------------------------------------------------------------------------
__global__ __launch_bounds__(256) void dw_high_kernel(
    const float* __restrict__ hf, const float* __restrict__ w,
    float* __restrict__ out) {
  int t = blockIdx.x * blockDim.x + threadIdx.x;
  if (t >= BB * CC * HHH * HWW) return;
  int x = t & 63;
  int y = (t >> 6) & 63;
  int c = (t >> 12) & 63;
  int b = t >> 18;
  const float* img = hf + ((size_t)(b * CC + c)) * (HHH * HWW);
  const float* wc = w + c * 9;
  float acc = 0.f;
#pragma unroll
  for (int dy = 0; dy < 3; ++dy) {
    int yy = y + dy - 1;
    if (yy < 0 || yy >= HHH) continue;
#pragma unroll
    for (int dx = 0; dx < 3; ++dx) {
      int xx = x + dx - 1;
      if (xx < 0 || xx >= HWW) continue;
      acc = fmaf(img[yy * HWW + xx], wc[dy * 3 + dx], acc);
    }
  }
  out[t] = acc;
}

// ---------------------------------------------------------------------------
// K2: grid flat 1024 (b = bid&7 -> XCD-affine, y = bid>>3), block 512.
//  Thread (x = tid&127, q = tid>>7) computes 16 channels c = q*16+j:
//  l = dw3x3(low), h = bilinear-up(h_small). Writes sump row (y+1) in
//  [px][ch] bf16 layout via LDS transpose; reduces gate stats in-block.
// ---------------------------------------------------------------------------
__global__ __launch_bounds__(512) void fuse_sum_stats_kernel(
    const float* __restrict__ low, const float* __restrict__ hsm,
    const float* __restrict__ wl, unsigned short* __restrict__ sump,
    float* __restrict__ gate_in) {
  __shared__ unsigned short sumS[128 * 64];  // 16 KB, XOR-swizzled
  __shared__ float sh[4][4][128];            // 8 KB stats

  const int bid = blockIdx.x;
  const int b = bid & 7;
  const int y = bid >> 3;
  const int tid = threadIdx.x;
  const int x = tid & 127;
  const int q = tid >> 7;

  // bilinear-up coords (64 -> 128, half-pixel)
  float sy = 0.5f * y - 0.25f;
  float sx = 0.5f * x - 0.25f;
  float y0f = floorf(sy), x0f = floorf(sx);
  float wy = sy - y0f, wx = sx - x0f;
  int iy0 = (int)y0f, ix0 = (int)x0f;
  int iy0c = max(0, min(HHH - 1, iy0));
  int iy1c = max(0, min(HHH - 1, iy0 + 1));
  int ix0c = max(0, min(HWW - 1, ix0));
  int ix1c = max(0, min(HWW - 1, ix0 + 1));
  float w00 = (1.f - wy) * (1.f - wx), w01 = (1.f - wy) * wx;
  float w10 = wy * (1.f - wx), w11 = wy * wx;

  float hmean = 0.f, lmean = 0.f;
  float hmax = -3.402823466e+38f, lmax = -3.402823466e+38f;

  unsigned short sv[16];
#pragma unroll 4
  for (int j = 0; j < 16; ++j) {
    const int c = q * 16 + j;
    const float* limg = low + ((size_t)(b * CC + c)) * (LHH * LWW);
    const float* wc = wl + c * 9;
    float l = 0.f;
#pragma unroll
    for (int dy = 0; dy < 3; ++dy) {
      int yy = y + dy - 1;
      if (yy < 0 || yy >= LHH) continue;
#pragma unroll
      for (int dx = 0; dx < 3; ++dx) {
        int xx = x + dx - 1;
        if (xx < 0 || xx >= LWW) continue;
        l = fmaf(limg[yy * LWW + xx], wc[dy * 3 + dx], l);
      }
    }
    const float* himg = hsm + ((size_t)(b * CC + c)) * (HHH * HWW);
    float h = w00 * himg[iy0c * HWW + ix0c] + w01 * himg[iy0c * HWW + ix1c] +
              w10 * himg[iy1c * HWW + ix0c] + w11 * himg[iy1c * HWW + ix1c];
    sv[j] = f2bf(l + h);
    hmean += h;
    lmean += l;
    hmax = fmaxf(hmax, h);
    lmax = fmaxf(lmax, l);
  }

  // pack 16 shorts -> two b128 LDS writes at swizzled addr
  {
    unsigned int pk[8];
#pragma unroll
    for (int j = 0; j < 8; ++j)
      pk[j] = (unsigned)sv[2 * j] | ((unsigned)sv[2 * j + 1] << 16);
    const int u0 = (x * 128 + q * 32) ^ ((x & 7) << 4);
    const int u1 = (x * 128 + q * 32 + 16) ^ ((x & 7) << 4);
    *(short8v*)((char*)sumS + u0) = *(short8v*)&pk[0];
    *(short8v*)((char*)sumS + u1) = *(short8v*)&pk[4];
  }
  sh[0][q][x] = hmean;
  sh[1][q][x] = lmean;
  sh[2][q][x] = hmax;
  sh[3][q][x] = lmax;
  __syncthreads();

  // coalesced write-out: 16 KB -> global row (y+1), px 1..128
  {
    char* dst = (char*)sump + (size_t)b * SIMGB + (size_t)(y + 1) * SROWB + 128;
#pragma unroll
    for (int pass = 0; pass < 2; ++pass) {
      int o = (tid + pass * 512) * 16;
      int L = o ^ (((o >> 7) & 7) << 4);
      *(short8v*)(dst + o) = *(const short8v*)((const char*)sumS + L);
    }
  }
  // stats reduce: tid -> (s = tid>>7, x)
  {
    const int s = q;
    float v0 = sh[s][0][x], v1 = sh[s][1][x], v2 = sh[s][2][x],
          v3 = sh[s][3][x];
    float r;
    if (s < 2)
      r = (v0 + v1 + v2 + v3) * (1.0f / CC);
    else
      r = fmaxf(fmaxf(v0, v1), fmaxf(v2, v3));
    gate_in[((size_t)(b * 4 + s)) * 16384 + y * 128 + x] = r;
  }
}

// ---------------------------------------------------------------------------
// K3: gate conv 4->1 3x3 + sigmoid
// ---------------------------------------------------------------------------
__global__ __launch_bounds__(256) void gate_kernel(
    const float* __restrict__ gate_in, const float* __restrict__ wg,
    float* __restrict__ gates) {
  int t = blockIdx.x * blockDim.x + threadIdx.x;
  if (t >= BB * LHH * LWW) return;
  int x = t & 127;
  int y = (t >> 7) & 127;
  int b = t >> 14;
  float acc = 0.f;
#pragma unroll
  for (int ic = 0; ic < 4; ++ic) {
    const float* img = gate_in + ((size_t)(b * 4 + ic)) * (LHH * LWW);
    const float* wc = wg + ic * 9;
#pragma unroll
    for (int dy = 0; dy < 3; ++dy) {
      int yy = y + dy - 1;
      if (yy < 0 || yy >= LHH) continue;
#pragma unroll
      for (int dx = 0; dx < 3; ++dx) {
        int xx = x + dx - 1;
        if (xx < 0 || xx >= LWW) continue;
        acc = fmaf(img[yy * LWW + xx], wc[dy * 3 + dx], acc);
      }
    }
  }
  gates[t] = 1.0f / (1.0f + expf(-acc));
}

// ---------------------------------------------------------------------------
// prep: B_t[oc'][k] bf16, k = (dy*3+dx)*64 + ci.
//  INTERLEAVED oc': oc' = c*4 + j, orig_oc = (j>>1)*128 + 2*c + (j&1),
//  so the 4 flow components of output channel c are consecutive rows.
// ---------------------------------------------------------------------------
__global__ __launch_bounds__(256) void prep_bt_kernel(
    const float* __restrict__ wflow, unsigned short* __restrict__ bt) {
  int t = blockIdx.x * blockDim.x + threadIdx.x;
  if (t >= 256 * BTS) return;
  int oc2 = t / BTS;
  int kd = t - oc2 * BTS;
  unsigned short v = 0;
  if (kd < 576) {
    int c = oc2 >> 2;
    int j = oc2 & 3;
    int orig = (j >> 1) * 128 + 2 * c + (j & 1);
    int dydx = kd >> 6;
    int ci = kd & 63;
    v = f2bf(wflow[(orig * 64 + ci) * 9 + dydx]);
  }
  bt[t] = v;
}

// ---------------------------------------------------------------------------
// zero-padded bilinear sample
// ---------------------------------------------------------------------------
__device__ __forceinline__ float bilin0(const float* __restrict__ img, int H,
                                        int W, float gx, float gy) {
  float x0f = floorf(gx), y0f = floorf(gy);
  float wx1 = gx - x0f, wy1 = gy - y0f;
  int x0 = (int)x0f, y0 = (int)y0f;
  float r = 0.f;
  if (x0 >= 0 && x0 < W && y0 >= 0 && y0 < H)
    r = fmaf(img[y0 * W + x0], (1.f - wx1) * (1.f - wy1), r);
  if (x0 + 1 >= 0 && x0 + 1 < W && y0 >= 0 && y0 < H)
    r = fmaf(img[y0 * W + x0 + 1], wx1 * (1.f - wy1), r);
  if (x0 >= 0 && x0 < W && y0 + 1 >= 0 && y0 + 1 < H)
    r = fmaf(img[(y0 + 1) * W + x0], (1.f - wx1) * wy1, r);
  if (x0 + 1 >= 0 && x0 + 1 < W && y0 + 1 >= 0 && y0 + 1 < H)
    r = fmaf(img[(y0 + 1) * W + x0 + 1], wx1 * wy1, r);
  return r;
}

// ---------------------------------------------------------------------------
// K4: fused flow-GEMM + warp + blend. grid flat 1024 (b = bid&7).
//  Stage rows y..y+2 of sump into LDS once (XOR-swizzled); barrier-free
//  K-loop with SWAPPED operands: D = [oc' x pixel]. With interleaved bt,
//  lane (lr,lg) of frag (mf,nf) holds ALL 4 flow components of
//  (pixel = wr*64+mf*16+lr, channel = wc*16+nf*4+lg) in acc[mf][nf][0..3]
//  -> combine entirely in registers, no flow LDS, no extra barriers.
// ---------------------------------------------------------------------------
__global__ __launch_bounds__(512, 4) void flow_gemm_combine_kernel(
    const unsigned short* __restrict__ sump,
    const unsigned short* __restrict__ bt, const float* __restrict__ low,
    const float* __restrict__ high, const float* __restrict__ gates,
    float* __restrict__ out) {
  __shared__ unsigned short ldsU[3 * 8320];  // rowCache: 49920 B

  const int bid = blockIdx.x;
  const int b = bid & 7;
  const int y = bid >> 3;
  const int tid = threadIdx.x;
  const int lane = tid & 63;
  const int wid = tid >> 6;
  const int wr = wid >> 2;  // pixel-half (x: wr*64 .. +63)
  const int wc = wid & 3;   // channel-quarter (c: wc*16 .. +15)
  const int lr = lane & 15;
  const int lg = lane >> 4;

  // ---- stage rows y..y+2 (contiguous 49920 B in global), XOR-swizzled
  {
    const char* src = (const char*)sump + (size_t)b * SIMGB + (size_t)y * SROWB;
    char* dstb = (char*)ldsU;
    for (int o = tid * 16; o < 3 * SROWB; o += 512 * 16) {
      int L = o ^ (((o >> 7) & 7) << 4);
      *(short8v*)(dstb + L) = *(const short8v*)(src + o);
    }
  }
  __syncthreads();

  f32x4 acc[4][4];
#pragma unroll
  for (int i = 0; i < 4; ++i)
#pragma unroll
    for (int j = 0; j < 4; ++j) acc[i][j] = (f32x4){0.f, 0.f, 0.f, 0.f};

  const char* rc = (const char*)ldsU;
  for (int dydx = 0; dydx < 9; ++dydx) {
    const int dy = dydx / 3;
    const int dx = dydx - dy * 3;
#pragma unroll
    for (int cc = 0; cc < 2; ++cc) {
      short8v af[4], bfr[4];
#pragma unroll
      for (int mf = 0; mf < 4; ++mf) {
        const int p = dy * 130 + dx + wr * 64 + mf * 16 + lr;
        const int fa = (p * 128 + cc * 64 + lg * 16) ^ ((p & 7) << 4);
        af[mf] = *(const short8v*)(rc + fa);
      }
#pragma unroll
      for (int nf = 0; nf < 4; ++nf)
        bfr[nf] = *(const short8v*)&bt[(size_t)(wc * 64 + nf * 16 + lr) * BTS +
                                       dydx * 64 + cc * 32 + lg * 8];
      // operands SWAPPED: A = weights (rows = oc'), B = pixels (cols = x)
#pragma unroll
      for (int mf = 0; mf < 4; ++mf)
#pragma unroll
        for (int nf = 0; nf < 4; ++nf)
          acc[mf][nf] = __builtin_amdgcn_mfma_f32_16x16x32_bf16(
              bfr[nf], af[mf], acc[mf][nf], 0, 0, 0);
    }
  }

  // ---- combine straight from registers (no barrier needed)
  const float* lowb = low + (size_t)b * CC * 16384;
  const float* highb = high + (size_t)b * CC * 4096;
  float* outb = out + (size_t)b * CC * 16384;
  const float by = -1.0f + y * (2.0f / 127.0f);
  const float gyh_b = (by + 1.0f) * 31.5f;  // + a1 * 63/256
  const float gyl_b = (by + 1.0f) * 63.5f;  // + a3 * 127/256

#pragma unroll
  for (int mf = 0; mf < 4; ++mf) {
    const int x = wr * 64 + mf * 16 + lr;
    const float g = gates[b * 16384 + y * 128 + x];
    const float bx = -1.0f + x * (2.0f / 127.0f);
    const float gxh_b = (bx + 1.0f) * 31.5f;
    const float gxl_b = (bx + 1.0f) * 63.5f;
#pragma unroll
    for (int nf = 0; nf < 4; ++nf) {
      const int c = wc * 16 + nf * 4 + lg;
      const float a0 = acc[mf][nf][0];
      const float a1 = acc[mf][nf][1];
      const float a2 = acc[mf][nf][2];
      const float a3 = acc[mf][nf][3];

      float gxh = fmaf(a0, 63.0f / 256.0f, gxh_b);
      float gyh = fmaf(a1, 63.0f / 256.0f, gyh_b);
      float hwv = bilin0(highb + (size_t)c * 4096, HHH, HWW, gxh, gyh);

      float gxl = fmaf(a2, 127.0f / 256.0f, gxl_b);
      float gyl = fmaf(a3, 127.0f / 256.0f, gyl_b);
      float lwv = bilin0(lowb + (size_t)c * 16384, LHH, LWW, gxl, gyl);

      outb[(size_t)c * 16384 + y * 128 + x] = fmaf(g, hwv - lwv, lwv);
    }
  }
}

// ---------------------------------------------------------------------------
extern "C" void kernel_launch(void* const* d_in, const int* in_sizes, int n_in,
                              void* d_out, int out_size, void* d_ws,
                              size_t ws_size, hipStream_t stream) {
  const float* low = (const float*)d_in[0];
  const float* high = (const float*)d_in[1];
  const float* w_conv_l = (const float*)d_in[2];
  const float* w_conv_h = (const float*)d_in[3];
  const float* w_flow = (const float*)d_in[4];
  const float* w_gate = (const float*)d_in[5];
  float* out = (float*)d_out;
  char* ws = (char*)d_ws;

  const size_t OFF_HSMALL = 0;         //  8,388,608
  const size_t OFF_SUMP = 8388608;     // 17,305,600 (bf16 [b][row][px][ch])
  const size_t OFF_GATEIN = 25694208;  //  2,097,152
  const size_t OFF_GATES = 27791360;   //    524,288
  const size_t OFF_BT = 28315648;      //    299,008

  float* h_small = (float*)(ws + OFF_HSMALL);
  unsigned short* sump = (unsigned short*)(ws + OFF_SUMP);
  float* gate_in = (float*)(ws + OFF_GATEIN);
  float* gates = (float*)(ws + OFF_GATES);
  unsigned short* bt = (unsigned short*)(ws + OFF_BT);

  zero_border_kernel<<<(8 * 4128 + 255) / 256, 256, 0, stream>>>(sump);
  dw_high_kernel<<<(BB * CC * HHH * HWW + 255) / 256, 256, 0, stream>>>(
      high, w_conv_h, h_small);
  prep_bt_kernel<<<(256 * BTS + 255) / 256, 256, 0, stream>>>(w_flow, bt);
  fuse_sum_stats_kernel<<<1024, 512, 0, stream>>>(low, h_small, w_conv_l, sump,
                                                  gate_in);
  gate_kernel<<<(BB * LHH * LWW + 255) / 256, 256, 0, stream>>>(gate_in,
                                                                w_gate, gates);
  flow_gemm_combine_kernel<<<1024, 512, 0, stream>>>(sump, bt, low, high,
                                                     gates, out);
}

// Round 6
// 147.783 us; speedup vs baseline: 8.1689x; 1.3902x over previous
//
#include <hip/hip_runtime.h>
#include <math.h>

#define BB 8
#define CC 64
#define LHH 128
#define LWW 128
#define HHH 64
#define HWW 64

typedef __attribute__((ext_vector_type(8))) short short8v;
typedef __attribute__((ext_vector_type(4))) float f32x4;

#define BTS 584   // B_t row stride (shorts): 576 + 8 pad
// sump layout: [b][row:130][px:130][ch:64] bf16; row = 8320 shorts = 16640 B
#define SROWB 16640          // bytes per global row
#define SIMGB (130 * SROWB)  // bytes per image
#define KROWB 8448           // K4 LDS row stride: 66 px * 128 B

__device__ __forceinline__ unsigned short f2bf(float f) {
  unsigned u = __float_as_uint(f);
  unsigned r = (u + 0x7fffu + ((u >> 16) & 1u)) >> 16;
  return (unsigned short)r;
}

// ---------------------------------------------------------------------------
// K0: zero the padded borders of sump (528 KB instead of 17 MB memset)
// ---------------------------------------------------------------------------
__global__ __launch_bounds__(256) void zero_border_kernel(
    unsigned short* __restrict__ sump) {
  int t = blockIdx.x * blockDim.x + threadIdx.x;
  if (t >= 8 * 4128) return;
  int b = t / 4128;
  int r = t - b * 4128;
  char* base = (char*)sump + (size_t)b * SIMGB;
  char* dst;
  if (r < 2080) {  // rows 0 and 129 full
    int row = (r < 1040) ? 0 : 129;
    int o = (r % 1040) * 16;
    dst = base + (size_t)row * SROWB + o;
  } else {  // rows 1..128, px 0 and 129 (128 B each)
    int r2 = r - 2080;
    int row = 1 + (r2 >> 4);
    int idx = r2 & 15;
    int side = idx >> 3;
    int o = (idx & 7) * 16;
    dst = base + (size_t)row * SROWB + side * (129 * 128) + o;
  }
  *(short8v*)dst = (short8v){0, 0, 0, 0, 0, 0, 0, 0};
}

// ---------------------------------------------------------------------------
// K1: depthwise 3x3 on high_feature -> h_small, branchless taps
// ---------------------------------------------------------------------------
__global__ __launch_bounds__(256) void dw_high_kernel(
    const float* __restrict__ hf, const float* __restrict__ w,
    float* __restrict__ out) {
  int t = blockIdx.x * blockDim.x + threadIdx.x;
  if (t >= BB * CC * HHH * HWW) return;
  int x = t & 63;
  int y = (t >> 6) & 63;
  int c = (t >> 12) & 63;
  int b = t >> 18;
  const float* img = hf + ((size_t)(b * CC + c)) * (HHH * HWW);
  const float* wc = w + c * 9;
  const int xm = max(x - 1, 0), xp = min(x + 1, 63);
  const int ym = max(y - 1, 0), yp = min(y + 1, 63);
  const float mL = x > 0 ? 1.f : 0.f, mR = x < 63 ? 1.f : 0.f;
  const float mT = y > 0 ? 1.f : 0.f, mB = y < 63 ? 1.f : 0.f;
  const float* r0 = img + ym * 64;
  const float* r1 = img + y * 64;
  const float* r2 = img + yp * 64;
  float t0 = (wc[0] * mL) * r0[xm] + wc[1] * r0[x] + (wc[2] * mR) * r0[xp];
  float t1 = (wc[3] * mL) * r1[xm] + wc[4] * r1[x] + (wc[5] * mR) * r1[xp];
  float t2 = (wc[6] * mL) * r2[xm] + wc[7] * r2[x] + (wc[8] * mR) * r2[xp];
  out[t] = mT * t0 + t1 + mB * t2;
}

// ---------------------------------------------------------------------------
// K2: grid flat 1024 (b = bid&7, y = bid>>3), block 512.
//  Thread (x, q) computes 16 channels; branchless dw taps; writes sump row
//  (y+1) in [px][ch] layout via LDS transpose; in-block gate stats.
// ---------------------------------------------------------------------------
__global__ __launch_bounds__(512) void fuse_sum_stats_kernel(
    const float* __restrict__ low, const float* __restrict__ hsm,
    const float* __restrict__ wl, unsigned short* __restrict__ sump,
    float* __restrict__ gate_in) {
  __shared__ unsigned short sumS[128 * 64];  // 16 KB, XOR-swizzled
  __shared__ float sh[4][4][128];            // 8 KB stats

  const int bid = blockIdx.x;
  const int b = bid & 7;
  const int y = bid >> 3;
  const int tid = threadIdx.x;
  const int x = tid & 127;
  const int q = tid >> 7;

  // bilinear-up coords (64 -> 128, half-pixel)
  float sy = 0.5f * y - 0.25f;
  float sx = 0.5f * x - 0.25f;
  float y0f = floorf(sy), x0f = floorf(sx);
  float wy = sy - y0f, wx = sx - x0f;
  int iy0 = (int)y0f, ix0 = (int)x0f;
  int iy0c = max(0, min(HHH - 1, iy0));
  int iy1c = max(0, min(HHH - 1, iy0 + 1));
  int ix0c = max(0, min(HWW - 1, ix0));
  int ix1c = max(0, min(HWW - 1, ix0 + 1));
  float w00 = (1.f - wy) * (1.f - wx), w01 = (1.f - wy) * wx;
  float w10 = wy * (1.f - wx), w11 = wy * wx;

  // branchless dw masks / clamped offsets
  const int xm = max(x - 1, 0), xp = min(x + 1, 127);
  const int ym = max(y - 1, 0), yp = min(y + 1, 127);
  const float mL = x > 0 ? 1.f : 0.f, mR = x < 127 ? 1.f : 0.f;
  const float mT = y > 0 ? 1.f : 0.f, mB = y < 127 ? 1.f : 0.f;

  float hmean = 0.f, lmean = 0.f;
  float hmax = -3.402823466e+38f, lmax = -3.402823466e+38f;

  unsigned short sv[16];
#pragma unroll 4
  for (int j = 0; j < 16; ++j) {
    const int c = q * 16 + j;
    const float* limg = low + ((size_t)(b * CC + c)) * (LHH * LWW);
    const float* wc = wl + c * 9;
    const float* r0 = limg + ym * 128;
    const float* r1 = limg + y * 128;
    const float* r2 = limg + yp * 128;
    float t0 = (wc[0] * mL) * r0[xm] + wc[1] * r0[x] + (wc[2] * mR) * r0[xp];
    float t1 = (wc[3] * mL) * r1[xm] + wc[4] * r1[x] + (wc[5] * mR) * r1[xp];
    float t2 = (wc[6] * mL) * r2[xm] + wc[7] * r2[x] + (wc[8] * mR) * r2[xp];
    float l = mT * t0 + t1 + mB * t2;

    const float* himg = hsm + ((size_t)(b * CC + c)) * (HHH * HWW);
    float h = w00 * himg[iy0c * HWW + ix0c] + w01 * himg[iy0c * HWW + ix1c] +
              w10 * himg[iy1c * HWW + ix0c] + w11 * himg[iy1c * HWW + ix1c];
    sv[j] = f2bf(l + h);
    hmean += h;
    lmean += l;
    hmax = fmaxf(hmax, h);
    lmax = fmaxf(lmax, l);
  }

  // pack 16 shorts -> two b128 LDS writes at swizzled addr
  {
    unsigned int pk[8];
#pragma unroll
    for (int j = 0; j < 8; ++j)
      pk[j] = (unsigned)sv[2 * j] | ((unsigned)sv[2 * j + 1] << 16);
    const int u0 = (x * 128 + q * 32) ^ ((x & 7) << 4);
    const int u1 = (x * 128 + q * 32 + 16) ^ ((x & 7) << 4);
    *(short8v*)((char*)sumS + u0) = *(short8v*)&pk[0];
    *(short8v*)((char*)sumS + u1) = *(short8v*)&pk[4];
  }
  sh[0][q][x] = hmean;
  sh[1][q][x] = lmean;
  sh[2][q][x] = hmax;
  sh[3][q][x] = lmax;
  __syncthreads();

  // coalesced write-out: 16 KB -> global row (y+1), px 1..128
  {
    char* dst = (char*)sump + (size_t)b * SIMGB + (size_t)(y + 1) * SROWB + 128;
#pragma unroll
    for (int pass = 0; pass < 2; ++pass) {
      int o = (tid + pass * 512) * 16;
      int L = o ^ (((o >> 7) & 7) << 4);
      *(short8v*)(dst + o) = *(const short8v*)((const char*)sumS + L);
    }
  }
  // stats reduce: tid -> (s = q, x)
  {
    const int s = q;
    float v0 = sh[s][0][x], v1 = sh[s][1][x], v2 = sh[s][2][x],
          v3 = sh[s][3][x];
    float r;
    if (s < 2)
      r = (v0 + v1 + v2 + v3) * (1.0f / CC);
    else
      r = fmaxf(fmaxf(v0, v1), fmaxf(v2, v3));
    gate_in[((size_t)(b * 4 + s)) * 16384 + y * 128 + x] = r;
  }
}

// ---------------------------------------------------------------------------
// K3: gate conv 4->1 3x3 + sigmoid, branchless
// ---------------------------------------------------------------------------
__global__ __launch_bounds__(256) void gate_kernel(
    const float* __restrict__ gate_in, const float* __restrict__ wg,
    float* __restrict__ gates) {
  int t = blockIdx.x * blockDim.x + threadIdx.x;
  if (t >= BB * LHH * LWW) return;
  int x = t & 127;
  int y = (t >> 7) & 127;
  int b = t >> 14;
  const int xm = max(x - 1, 0), xp = min(x + 1, 127);
  const int ym = max(y - 1, 0), yp = min(y + 1, 127);
  const float mL = x > 0 ? 1.f : 0.f, mR = x < 127 ? 1.f : 0.f;
  const float mT = y > 0 ? 1.f : 0.f, mB = y < 127 ? 1.f : 0.f;
  float acc = 0.f;
#pragma unroll
  for (int ic = 0; ic < 4; ++ic) {
    const float* img = gate_in + ((size_t)(b * 4 + ic)) * (LHH * LWW);
    const float* wc = wg + ic * 9;
    const float* r0 = img + ym * 128;
    const float* r1 = img + y * 128;
    const float* r2 = img + yp * 128;
    float t0 = (wc[0] * mL) * r0[xm] + wc[1] * r0[x] + (wc[2] * mR) * r0[xp];
    float t1 = (wc[3] * mL) * r1[xm] + wc[4] * r1[x] + (wc[5] * mR) * r1[xp];
    float t2 = (wc[6] * mL) * r2[xm] + wc[7] * r2[x] + (wc[8] * mR) * r2[xp];
    acc += mT * t0 + t1 + mB * t2;
  }
  gates[t] = 1.0f / (1.0f + expf(-acc));
}

// ---------------------------------------------------------------------------
// prep: B_t[oc'][k] bf16, k = (dy*3+dx)*64 + ci; oc' = c*4 + j interleave,
//  orig_oc = (j>>1)*128 + 2*c + (j&1)
// ---------------------------------------------------------------------------
__global__ __launch_bounds__(256) void prep_bt_kernel(
    const float* __restrict__ wflow, unsigned short* __restrict__ bt) {
  int t = blockIdx.x * blockDim.x + threadIdx.x;
  if (t >= 256 * BTS) return;
  int oc2 = t / BTS;
  int kd = t - oc2 * BTS;
  unsigned short v = 0;
  if (kd < 576) {
    int c = oc2 >> 2;
    int j = oc2 & 3;
    int orig = (j >> 1) * 128 + 2 * c + (j & 1);
    int dydx = kd >> 6;
    int ci = kd & 63;
    v = f2bf(wflow[(orig * 64 + ci) * 9 + dydx]);
  }
  bt[t] = v;
}

// ---------------------------------------------------------------------------
// branchless zero-padded bilinear sample: clamp indices, mask weights
// ---------------------------------------------------------------------------
__device__ __forceinline__ float bilin0(const float* __restrict__ img, int H,
                                        int W, float gx, float gy) {
  float x0f = floorf(gx), y0f = floorf(gy);
  float wx1 = gx - x0f, wy1 = gy - y0f;
  float wx0 = 1.f - wx1, wy0 = 1.f - wy1;
  int x0 = (int)x0f, y0 = (int)y0f;
  int x1 = x0 + 1, y1 = y0 + 1;
  float mx0 = ((unsigned)x0 < (unsigned)W) ? wx0 : 0.f;
  float mx1 = ((unsigned)x1 < (unsigned)W) ? wx1 : 0.f;
  float my0 = ((unsigned)y0 < (unsigned)H) ? wy0 : 0.f;
  float my1 = ((unsigned)y1 < (unsigned)H) ? wy1 : 0.f;
  int x0c = min(max(x0, 0), W - 1), x1c = min(max(x1, 0), W - 1);
  int y0c = min(max(y0, 0), H - 1), y1c = min(max(y1, 0), H - 1);
  float v00 = img[y0c * W + x0c];
  float v01 = img[y0c * W + x1c];
  float v10 = img[y1c * W + x0c];
  float v11 = img[y1c * W + x1c];
  return my0 * (mx0 * v00 + mx1 * v01) + my1 * (mx0 * v10 + mx1 * v11);
}

// ---------------------------------------------------------------------------
// K4: fused flow-GEMM + warp + blend. grid flat 2048:
//  b = bid&7 (XCD), y = (bid>>3)&127, xh = bid>>10 (64-px half).
//  8 waves, each owns 32 oc' x 64 px (acc[4][2]); stage 3x66-px window
//  (25344 B) once, barrier-free K-loop; combine from registers, branchless
//  gathers.
// ---------------------------------------------------------------------------
__global__ __launch_bounds__(512, 6) void flow_gemm_combine_kernel(
    const unsigned short* __restrict__ sump,
    const unsigned short* __restrict__ bt, const float* __restrict__ low,
    const float* __restrict__ high, const float* __restrict__ gates,
    float* __restrict__ out) {
  __shared__ unsigned short ldsU[3 * 4224];  // 25344 B

  const int bid = blockIdx.x;
  const int b = bid & 7;
  const int y = (bid >> 3) & 127;
  const int xh = bid >> 10;
  const int tid = threadIdx.x;
  const int lane = tid & 63;
  const int wid = tid >> 6;  // oc' block = wid*32
  const int lr = lane & 15;
  const int lg = lane >> 4;

  // ---- stage rows y..y+2, px window xh*64 .. xh*64+65, XOR-swizzled
  {
    const char* src = (const char*)sump + (size_t)b * SIMGB +
                      (size_t)y * SROWB + xh * 8192;
    char* dstb = (char*)ldsU;
    for (int i = tid; i < 1584; i += 512) {
      int seg = i / 528;
      int wo = (i - seg * 528) * 16;
      int o = seg * KROWB + wo;
      int L = o ^ (((o >> 7) & 7) << 4);
      *(short8v*)(dstb + L) = *(const short8v*)(src + seg * SROWB + wo);
    }
  }
  __syncthreads();

  f32x4 acc[4][2];
#pragma unroll
  for (int i = 0; i < 4; ++i)
#pragma unroll
    for (int j = 0; j < 2; ++j) acc[i][j] = (f32x4){0.f, 0.f, 0.f, 0.f};

  const char* rc = (const char*)ldsU;
  const unsigned short* btw = bt + (size_t)(wid * 32 + lr) * BTS + lg * 8;
  for (int dydx = 0; dydx < 9; ++dydx) {
    const int dy = dydx / 3;
    const int dxl = dydx - dy * 3;
#pragma unroll
    for (int cc = 0; cc < 2; ++cc) {
      short8v af[4], bfr[2];
#pragma unroll
      for (int mf = 0; mf < 4; ++mf) {
        const int p = dy * 66 + dxl + mf * 16 + lr;
        const int fa = (p * 128 + cc * 64 + lg * 16) ^ ((p & 7) << 4);
        af[mf] = *(const short8v*)(rc + fa);
      }
#pragma unroll
      for (int nf = 0; nf < 2; ++nf)
        bfr[nf] = *(const short8v*)&btw[nf * 16 * BTS + dydx * 64 + cc * 32];
      // swapped operands: D = [oc' x px]
#pragma unroll
      for (int mf = 0; mf < 4; ++mf)
#pragma unroll
        for (int nf = 0; nf < 2; ++nf)
          acc[mf][nf] = __builtin_amdgcn_mfma_f32_16x16x32_bf16(
              bfr[nf], af[mf], acc[mf][nf], 0, 0, 0);
    }
  }

  // ---- combine from registers: lane (lr,lg) frag (mf,nf) holds all 4 flow
  // components of (px = xh*64 + mf*16 + lr, c = wid*8 + nf*4 + lg)
  const float* lowb = low + (size_t)b * CC * 16384;
  const float* highb = high + (size_t)b * CC * 4096;
  float* outb = out + (size_t)b * CC * 16384;
  const float by = -1.0f + y * (2.0f / 127.0f);
  const float gyh_b = (by + 1.0f) * 31.5f;
  const float gyl_b = (by + 1.0f) * 63.5f;
  const int xg0 = xh * 64;

#pragma unroll
  for (int mf = 0; mf < 4; ++mf) {
    const int x = xg0 + mf * 16 + lr;
    const float g = gates[b * 16384 + y * 128 + x];
    const float bx = -1.0f + x * (2.0f / 127.0f);
    const float gxh_b = (bx + 1.0f) * 31.5f;
    const float gxl_b = (bx + 1.0f) * 63.5f;
#pragma unroll
    for (int nf = 0; nf < 2; ++nf) {
      const int c = wid * 8 + nf * 4 + lg;
      const float a0 = acc[mf][nf][0];
      const float a1 = acc[mf][nf][1];
      const float a2 = acc[mf][nf][2];
      const float a3 = acc[mf][nf][3];

      float gxh = fmaf(a0, 63.0f / 256.0f, gxh_b);
      float gyh = fmaf(a1, 63.0f / 256.0f, gyh_b);
      float hwv = bilin0(highb + (size_t)c * 4096, HHH, HWW, gxh, gyh);

      float gxl = fmaf(a2, 127.0f / 256.0f, gxl_b);
      float gyl = fmaf(a3, 127.0f / 256.0f, gyl_b);
      float lwv = bilin0(lowb + (size_t)c * 16384, LHH, LWW, gxl, gyl);

      outb[(size_t)c * 16384 + y * 128 + x] = fmaf(g, hwv - lwv, lwv);
    }
  }
}

// ---------------------------------------------------------------------------
extern "C" void kernel_launch(void* const* d_in, const int* in_sizes, int n_in,
                              void* d_out, int out_size, void* d_ws,
                              size_t ws_size, hipStream_t stream) {
  const float* low = (const float*)d_in[0];
  const float* high = (const float*)d_in[1];
  const float* w_conv_l = (const float*)d_in[2];
  const float* w_conv_h = (const float*)d_in[3];
  const float* w_flow = (const float*)d_in[4];
  const float* w_gate = (const float*)d_in[5];
  float* out = (float*)d_out;
  char* ws = (char*)d_ws;

  const size_t OFF_HSMALL = 0;         //  8,388,608
  const size_t OFF_SUMP = 8388608;     // 17,305,600 (bf16 [b][row][px][ch])
  const size_t OFF_GATEIN = 25694208;  //  2,097,152
  const size_t OFF_GATES = 27791360;   //    524,288
  const size_t OFF_BT = 28315648;      //    299,008

  float* h_small = (float*)(ws + OFF_HSMALL);
  unsigned short* sump = (unsigned short*)(ws + OFF_SUMP);
  float* gate_in = (float*)(ws + OFF_GATEIN);
  float* gates = (float*)(ws + OFF_GATES);
  unsigned short* bt = (unsigned short*)(ws + OFF_BT);

  zero_border_kernel<<<(8 * 4128 + 255) / 256, 256, 0, stream>>>(sump);
  dw_high_kernel<<<(BB * CC * HHH * HWW + 255) / 256, 256, 0, stream>>>(
      high, w_conv_h, h_small);
  prep_bt_kernel<<<(256 * BTS + 255) / 256, 256, 0, stream>>>(w_flow, bt);
  fuse_sum_stats_kernel<<<1024, 512, 0, stream>>>(low, h_small, w_conv_l, sump,
                                                  gate_in);
  gate_kernel<<<(BB * LHH * LWW + 255) / 256, 256, 0, stream>>>(gate_in,
                                                                w_gate, gates);
  flow_gemm_combine_kernel<<<2048, 512, 0, stream>>>(sump, bt, low, high,
                                                     gates, out);
}

// Round 7
// 139.044 us; speedup vs baseline: 8.6823x; 1.0629x over previous
//
#include <hip/hip_runtime.h>
#include <math.h>

#define BB 8
#define CC 64
#define LHH 128
#define LWW 128
#define HHH 64
#define HWW 64

typedef __attribute__((ext_vector_type(8))) short short8v;
typedef __attribute__((ext_vector_type(4))) float f32x4;

#define BTS 584   // B_t row stride (shorts): 576 + 8 pad
// sump layout: [b][row:130][px:130][ch:64] bf16; row = 8320 shorts = 16640 B
#define SROWB 16640          // bytes per global row
#define SIMGB (130 * SROWB)  // bytes per image
#define KROWB 8448           // K4 LDS row stride: 66 px * 128 B

__device__ __forceinline__ unsigned short f2bf(float f) {
  unsigned u = __float_as_uint(f);
  unsigned r = (u + 0x7fffu + ((u >> 16) & 1u)) >> 16;
  return (unsigned short)r;
}

// ---------------------------------------------------------------------------
// K1: depthwise 3x3 on high_feature -> h_small (branchless), PLUS (appended
//  blocks) prep of B_t[oc'][k] bf16: oc' = c*4+j, orig = (j>>1)*128+2c+(j&1),
//  k = (dy*3+dx)*64 + ci.
// ---------------------------------------------------------------------------
__global__ __launch_bounds__(256) void dw_high_prep_kernel(
    const float* __restrict__ hf, const float* __restrict__ w,
    float* __restrict__ out, const float* __restrict__ wflow,
    unsigned short* __restrict__ bt) {
  if (blockIdx.x >= 8192) {  // prep_bt part
    int t = (blockIdx.x - 8192) * 256 + threadIdx.x;
    if (t >= 256 * BTS) return;
    int oc2 = t / BTS;
    int kd = t - oc2 * BTS;
    unsigned short v = 0;
    if (kd < 576) {
      int c = oc2 >> 2;
      int j = oc2 & 3;
      int orig = (j >> 1) * 128 + 2 * c + (j & 1);
      int dydx = kd >> 6;
      int ci = kd & 63;
      v = f2bf(wflow[(orig * 64 + ci) * 9 + dydx]);
    }
    bt[t] = v;
    return;
  }
  int t = blockIdx.x * 256 + threadIdx.x;
  int x = t & 63;
  int y = (t >> 6) & 63;
  int c = (t >> 12) & 63;
  int b = t >> 18;
  const float* img = hf + ((size_t)(b * CC + c)) * (HHH * HWW);
  const float* wc = w + c * 9;
  const int xm = max(x - 1, 0), xp = min(x + 1, 63);
  const int ym = max(y - 1, 0), yp = min(y + 1, 63);
  const float mL = x > 0 ? 1.f : 0.f, mR = x < 63 ? 1.f : 0.f;
  const float mT = y > 0 ? 1.f : 0.f, mB = y < 63 ? 1.f : 0.f;
  const float* r0 = img + ym * 64;
  const float* r1 = img + y * 64;
  const float* r2 = img + yp * 64;
  float t0 = (wc[0] * mL) * r0[xm] + wc[1] * r0[x] + (wc[2] * mR) * r0[xp];
  float t1 = (wc[3] * mL) * r1[xm] + wc[4] * r1[x] + (wc[5] * mR) * r1[xp];
  float t2 = (wc[6] * mL) * r2[xm] + wc[7] * r2[x] + (wc[8] * mR) * r2[xp];
  out[t] = mT * t0 + t1 + mB * t2;
}

// ---------------------------------------------------------------------------
// K2: grid flat 1024 (b = bid&7, y = bid>>3), block 512.
//  Thread (x, q) computes 16 channels; branchless dw taps; writes sump row
//  (y+1) in [px][ch] layout via LDS transpose; in-block gate stats; ALSO
//  zeroes this row's px0/px129 borders (and rows 0/129 when y==0).
// ---------------------------------------------------------------------------
__global__ __launch_bounds__(512) void fuse_sum_stats_kernel(
    const float* __restrict__ low, const float* __restrict__ hsm,
    const float* __restrict__ wl, unsigned short* __restrict__ sump,
    float* __restrict__ gate_in) {
  __shared__ unsigned short sumS[128 * 64];  // 16 KB, XOR-swizzled
  __shared__ float sh[4][4][128];            // 8 KB stats

  const int bid = blockIdx.x;
  const int b = bid & 7;
  const int y = bid >> 3;
  const int tid = threadIdx.x;
  const int x = tid & 127;
  const int q = tid >> 7;
  char* sbase = (char*)sump + (size_t)b * SIMGB;

  // border zeroing (replaces zero_border_kernel)
  {
    const short8v z = {0, 0, 0, 0, 0, 0, 0, 0};
    if (y == 0) {
      for (int i = tid; i < 2080; i += 512) {
        int row = (i < 1040) ? 0 : 129;
        int o = (i % 1040) * 16;
        *(short8v*)(sbase + (size_t)row * SROWB + o) = z;
      }
    }
    if (tid < 16) {  // this row's px0 / px129 (128 B each)
      int side = tid >> 3;
      int o = (tid & 7) * 16;
      *(short8v*)(sbase + (size_t)(y + 1) * SROWB + side * (129 * 128) + o) = z;
    }
  }

  // bilinear-up coords (64 -> 128, half-pixel)
  float sy = 0.5f * y - 0.25f;
  float sx = 0.5f * x - 0.25f;
  float y0f = floorf(sy), x0f = floorf(sx);
  float wy = sy - y0f, wx = sx - x0f;
  int iy0 = (int)y0f, ix0 = (int)x0f;
  int iy0c = max(0, min(HHH - 1, iy0));
  int iy1c = max(0, min(HHH - 1, iy0 + 1));
  int ix0c = max(0, min(HWW - 1, ix0));
  int ix1c = max(0, min(HWW - 1, ix0 + 1));
  float w00 = (1.f - wy) * (1.f - wx), w01 = (1.f - wy) * wx;
  float w10 = wy * (1.f - wx), w11 = wy * wx;

  // branchless dw masks / clamped offsets
  const int xm = max(x - 1, 0), xp = min(x + 1, 127);
  const int ym = max(y - 1, 0), yp = min(y + 1, 127);
  const float mL = x > 0 ? 1.f : 0.f, mR = x < 127 ? 1.f : 0.f;
  const float mT = y > 0 ? 1.f : 0.f, mB = y < 127 ? 1.f : 0.f;

  float hmean = 0.f, lmean = 0.f;
  float hmax = -3.402823466e+38f, lmax = -3.402823466e+38f;

  unsigned short sv[16];
#pragma unroll 4
  for (int j = 0; j < 16; ++j) {
    const int c = q * 16 + j;
    const float* limg = low + ((size_t)(b * CC + c)) * (LHH * LWW);
    const float* wc = wl + c * 9;
    const float* r0 = limg + ym * 128;
    const float* r1 = limg + y * 128;
    const float* r2 = limg + yp * 128;
    float t0 = (wc[0] * mL) * r0[xm] + wc[1] * r0[x] + (wc[2] * mR) * r0[xp];
    float t1 = (wc[3] * mL) * r1[xm] + wc[4] * r1[x] + (wc[5] * mR) * r1[xp];
    float t2 = (wc[6] * mL) * r2[xm] + wc[7] * r2[x] + (wc[8] * mR) * r2[xp];
    float l = mT * t0 + t1 + mB * t2;

    const float* himg = hsm + ((size_t)(b * CC + c)) * (HHH * HWW);
    float h = w00 * himg[iy0c * HWW + ix0c] + w01 * himg[iy0c * HWW + ix1c] +
              w10 * himg[iy1c * HWW + ix0c] + w11 * himg[iy1c * HWW + ix1c];
    sv[j] = f2bf(l + h);
    hmean += h;
    lmean += l;
    hmax = fmaxf(hmax, h);
    lmax = fmaxf(lmax, l);
  }

  // pack 16 shorts -> two b128 LDS writes at swizzled addr
  {
    unsigned int pk[8];
#pragma unroll
    for (int j = 0; j < 8; ++j)
      pk[j] = (unsigned)sv[2 * j] | ((unsigned)sv[2 * j + 1] << 16);
    const int u0 = (x * 128 + q * 32) ^ ((x & 7) << 4);
    const int u1 = (x * 128 + q * 32 + 16) ^ ((x & 7) << 4);
    *(short8v*)((char*)sumS + u0) = *(short8v*)&pk[0];
    *(short8v*)((char*)sumS + u1) = *(short8v*)&pk[4];
  }
  sh[0][q][x] = hmean;
  sh[1][q][x] = lmean;
  sh[2][q][x] = hmax;
  sh[3][q][x] = lmax;
  __syncthreads();

  // coalesced write-out: 16 KB -> global row (y+1), px 1..128
  {
    char* dst = sbase + (size_t)(y + 1) * SROWB + 128;
#pragma unroll
    for (int pass = 0; pass < 2; ++pass) {
      int o = (tid + pass * 512) * 16;
      int L = o ^ (((o >> 7) & 7) << 4);
      *(short8v*)(dst + o) = *(const short8v*)((const char*)sumS + L);
    }
  }
  // stats reduce: tid -> (s = q, x)
  {
    const int s = q;
    float v0 = sh[s][0][x], v1 = sh[s][1][x], v2 = sh[s][2][x],
          v3 = sh[s][3][x];
    float r;
    if (s < 2)
      r = (v0 + v1 + v2 + v3) * (1.0f / CC);
    else
      r = fmaxf(fmaxf(v0, v1), fmaxf(v2, v3));
    gate_in[((size_t)(b * 4 + s)) * 16384 + y * 128 + x] = r;
  }
}

// ---------------------------------------------------------------------------
// branchless zero-padded bilinear sample: clamp indices, mask weights
// ---------------------------------------------------------------------------
__device__ __forceinline__ float bilin0(const float* __restrict__ img, int H,
                                        int W, float gx, float gy) {
  float x0f = floorf(gx), y0f = floorf(gy);
  float wx1 = gx - x0f, wy1 = gy - y0f;
  float wx0 = 1.f - wx1, wy0 = 1.f - wy1;
  int x0 = (int)x0f, y0 = (int)y0f;
  int x1 = x0 + 1, y1 = y0 + 1;
  float mx0 = ((unsigned)x0 < (unsigned)W) ? wx0 : 0.f;
  float mx1 = ((unsigned)x1 < (unsigned)W) ? wx1 : 0.f;
  float my0 = ((unsigned)y0 < (unsigned)H) ? wy0 : 0.f;
  float my1 = ((unsigned)y1 < (unsigned)H) ? wy1 : 0.f;
  int x0c = min(max(x0, 0), W - 1), x1c = min(max(x1, 0), W - 1);
  int y0c = min(max(y0, 0), H - 1), y1c = min(max(y1, 0), H - 1);
  float v00 = img[y0c * W + x0c];
  float v01 = img[y0c * W + x1c];
  float v10 = img[y1c * W + x0c];
  float v11 = img[y1c * W + x1c];
  return my0 * (mx0 * v00 + mx1 * v01) + my1 * (mx0 * v10 + mx1 * v11);
}

// ---------------------------------------------------------------------------
// K4: fused gate-conv + flow-GEMM + warp + blend. grid flat 4096:
//  b = bid&7 (XCD), y = (bid>>3)&127, xh = (bid>>10)&1, oh = bid>>11.
//  8 waves, each owns 16 oc' x 64 px (acc[4][1] -> 16 AGPR); 8 waves/SIMD
//  via launch_bounds(512,8). Gate conv for the 64 px computed by wave 0
//  into LDS. Combine straight from registers, branchless gathers.
// ---------------------------------------------------------------------------
__global__ __launch_bounds__(512, 8) void flow_gemm_combine_kernel(
    const unsigned short* __restrict__ sump,
    const unsigned short* __restrict__ bt, const float* __restrict__ low,
    const float* __restrict__ high, const float* __restrict__ gate_in,
    const float* __restrict__ wg, float* __restrict__ out) {
  __shared__ unsigned short ldsU[3 * 4224];  // 25344 B
  __shared__ float gateS[64];

  const int bid = blockIdx.x;
  const int b = bid & 7;
  const int y = (bid >> 3) & 127;
  const int xh = (bid >> 10) & 1;
  const int oh = bid >> 11;  // oc' half (0: oc'<128, 1: oc'>=128)
  const int tid = threadIdx.x;
  const int lane = tid & 63;
  const int wid = tid >> 6;
  const int lr = lane & 15;
  const int lg = lane >> 4;

  // ---- stage rows y..y+2, px window xh*64 .. xh*64+65, XOR-swizzled
  {
    const char* src =
        (const char*)sump + (size_t)b * SIMGB + (size_t)y * SROWB + xh * 8192;
    char* dstb = (char*)ldsU;
    for (int i = tid; i < 1584; i += 512) {
      int seg = i / 528;
      int wo = (i - seg * 528) * 16;
      int o = seg * KROWB + wo;
      int L = o ^ (((o >> 7) & 7) << 4);
      *(short8v*)(dstb + L) = *(const short8v*)(src + seg * SROWB + wo);
    }
  }

  // ---- gate conv for this block's 64 px (wave 0), branchless
  if (tid < 64) {
    const int x = xh * 64 + tid;
    const int xm = max(x - 1, 0), xp = min(x + 1, 127);
    const int ym = max(y - 1, 0), yp = min(y + 1, 127);
    const float mL = x > 0 ? 1.f : 0.f, mR = x < 127 ? 1.f : 0.f;
    const float mT = y > 0 ? 1.f : 0.f, mB = y < 127 ? 1.f : 0.f;
    const float* gi = gate_in + (size_t)b * 4 * 16384;
    float acc0 = 0.f;
#pragma unroll
    for (int ic = 0; ic < 4; ++ic) {
      const float* img = gi + ic * 16384;
      const float* wc = wg + ic * 9;
      const float* r0 = img + ym * 128;
      const float* r1 = img + y * 128;
      const float* r2 = img + yp * 128;
      float t0 = (wc[0] * mL) * r0[xm] + wc[1] * r0[x] + (wc[2] * mR) * r0[xp];
      float t1 = (wc[3] * mL) * r1[xm] + wc[4] * r1[x] + (wc[5] * mR) * r1[xp];
      float t2 = (wc[6] * mL) * r2[xm] + wc[7] * r2[x] + (wc[8] * mR) * r2[xp];
      acc0 += mT * t0 + t1 + mB * t2;
    }
    gateS[tid] = 1.0f / (1.0f + expf(-acc0));
  }
  __syncthreads();

  f32x4 acc[4];
#pragma unroll
  for (int i = 0; i < 4; ++i) acc[i] = (f32x4){0.f, 0.f, 0.f, 0.f};

  const char* rc = (const char*)ldsU;
  const unsigned short* btw =
      bt + (size_t)(oh * 128 + wid * 16 + lr) * BTS + lg * 8;
  for (int dydx = 0; dydx < 9; ++dydx) {
    const int dy = dydx / 3;
    const int dxl = dydx - dy * 3;
#pragma unroll
    for (int cc = 0; cc < 2; ++cc) {
      short8v af[4], bfr;
#pragma unroll
      for (int mf = 0; mf < 4; ++mf) {
        const int p = dy * 66 + dxl + mf * 16 + lr;
        const int fa = (p * 128 + cc * 64 + lg * 16) ^ ((p & 7) << 4);
        af[mf] = *(const short8v*)(rc + fa);
      }
      bfr = *(const short8v*)&btw[dydx * 64 + cc * 32];
      // swapped operands: D = [oc' x px]
#pragma unroll
      for (int mf = 0; mf < 4; ++mf)
        acc[mf] = __builtin_amdgcn_mfma_f32_16x16x32_bf16(bfr, af[mf], acc[mf],
                                                          0, 0, 0);
    }
  }

  // ---- combine from registers: lane (lr,lg) frag mf holds all 4 flow
  // components of (px = xh*64 + mf*16 + lr, c = oh*32 + wid*4 + lg)
  const int c = oh * 32 + wid * 4 + lg;
  const float* lowc = low + ((size_t)(b * CC + c)) * 16384;
  const float* highc = high + ((size_t)(b * CC + c)) * 4096;
  float* outc = out + ((size_t)(b * CC + c)) * 16384;
  const float by = -1.0f + y * (2.0f / 127.0f);
  const float gyh_b = (by + 1.0f) * 31.5f;
  const float gyl_b = (by + 1.0f) * 63.5f;
  const int xg0 = xh * 64;

#pragma unroll
  for (int mf = 0; mf < 4; ++mf) {
    const int x = xg0 + mf * 16 + lr;
    const float g = gateS[mf * 16 + lr];
    const float bx = -1.0f + x * (2.0f / 127.0f);
    const float gxh_b = (bx + 1.0f) * 31.5f;
    const float gxl_b = (bx + 1.0f) * 63.5f;

    float gxh = fmaf(acc[mf][0], 63.0f / 256.0f, gxh_b);
    float gyh = fmaf(acc[mf][1], 63.0f / 256.0f, gyh_b);
    float hwv = bilin0(highc, HHH, HWW, gxh, gyh);

    float gxl = fmaf(acc[mf][2], 127.0f / 256.0f, gxl_b);
    float gyl = fmaf(acc[mf][3], 127.0f / 256.0f, gyl_b);
    float lwv = bilin0(lowc, LHH, LWW, gxl, gyl);

    outc[y * 128 + x] = fmaf(g, hwv - lwv, lwv);
  }
}

// ---------------------------------------------------------------------------
extern "C" void kernel_launch(void* const* d_in, const int* in_sizes, int n_in,
                              void* d_out, int out_size, void* d_ws,
                              size_t ws_size, hipStream_t stream) {
  const float* low = (const float*)d_in[0];
  const float* high = (const float*)d_in[1];
  const float* w_conv_l = (const float*)d_in[2];
  const float* w_conv_h = (const float*)d_in[3];
  const float* w_flow = (const float*)d_in[4];
  const float* w_gate = (const float*)d_in[5];
  float* out = (float*)d_out;
  char* ws = (char*)d_ws;

  const size_t OFF_HSMALL = 0;         //  8,388,608
  const size_t OFF_SUMP = 8388608;     // 17,305,600 (bf16 [b][row][px][ch])
  const size_t OFF_GATEIN = 25694208;  //  2,097,152
  const size_t OFF_BT = 28315648;      //    299,008

  float* h_small = (float*)(ws + OFF_HSMALL);
  unsigned short* sump = (unsigned short*)(ws + OFF_SUMP);
  float* gate_in = (float*)(ws + OFF_GATEIN);
  unsigned short* bt = (unsigned short*)(ws + OFF_BT);

  // K1: dw-high (8192 blocks) + prep_bt (584 blocks appended)
  dw_high_prep_kernel<<<8192 + 584, 256, 0, stream>>>(high, w_conv_h, h_small,
                                                      w_flow, bt);
  // K2: sum + stats + sump borders
  fuse_sum_stats_kernel<<<1024, 512, 0, stream>>>(low, h_small, w_conv_l, sump,
                                                  gate_in);
  // K4: gate conv + flow GEMM + warp + blend
  flow_gemm_combine_kernel<<<4096, 512, 0, stream>>>(sump, bt, low, high,
                                                     gate_in, w_gate, out);
}

// Round 8
// 136.506 us; speedup vs baseline: 8.8438x; 1.0186x over previous
//
#include <hip/hip_runtime.h>
#include <math.h>

#define BB 8
#define CC 64
#define LHH 128
#define LWW 128
#define HHH 64
#define HWW 64

typedef __attribute__((ext_vector_type(8))) short short8v;
typedef __attribute__((ext_vector_type(4))) float f32x4;

// unaligned-capable float pair (align 4); gfx9+ global dwordx2 handles it
typedef struct __attribute__((packed, aligned(4))) {
  float x, y;
} f2u;

#define BTS 584   // B_t row stride (shorts): 576 + 8 pad
// sump layout: [b][row:130][px:130][ch:64] bf16; row = 8320 shorts = 16640 B
#define SROWB 16640          // bytes per global row
#define SIMGB (130 * SROWB)  // bytes per image
#define KROWB 8448           // K4 LDS row stride: 66 px * 128 B

__device__ __forceinline__ unsigned short f2bf(float f) {
  unsigned u = __float_as_uint(f);
  unsigned r = (u + 0x7fffu + ((u >> 16) & 1u)) >> 16;
  return (unsigned short)r;
}

// ---------------------------------------------------------------------------
// K1: depthwise 3x3 on high_feature -> h_small (branchless), PLUS (appended
//  blocks) prep of B_t[oc'][k] bf16: oc' = c*4+j, orig = (j>>1)*128+2c+(j&1),
//  k = (dy*3+dx)*64 + ci.
// ---------------------------------------------------------------------------
__global__ __launch_bounds__(256) void dw_high_prep_kernel(
    const float* __restrict__ hf, const float* __restrict__ w,
    float* __restrict__ out, const float* __restrict__ wflow,
    unsigned short* __restrict__ bt) {
  if (blockIdx.x >= 8192) {  // prep_bt part
    int t = (blockIdx.x - 8192) * 256 + threadIdx.x;
    if (t >= 256 * BTS) return;
    int oc2 = t / BTS;
    int kd = t - oc2 * BTS;
    unsigned short v = 0;
    if (kd < 576) {
      int c = oc2 >> 2;
      int j = oc2 & 3;
      int orig = (j >> 1) * 128 + 2 * c + (j & 1);
      int dydx = kd >> 6;
      int ci = kd & 63;
      v = f2bf(wflow[(orig * 64 + ci) * 9 + dydx]);
    }
    bt[t] = v;
    return;
  }
  int t = blockIdx.x * 256 + threadIdx.x;
  int x = t & 63;
  int y = (t >> 6) & 63;
  int c = (t >> 12) & 63;
  int b = t >> 18;
  const float* img = hf + ((size_t)(b * CC + c)) * (HHH * HWW);
  const float* wc = w + c * 9;
  const int xm = max(x - 1, 0), xp = min(x + 1, 63);
  const int ym = max(y - 1, 0), yp = min(y + 1, 63);
  const float mL = x > 0 ? 1.f : 0.f, mR = x < 63 ? 1.f : 0.f;
  const float mT = y > 0 ? 1.f : 0.f, mB = y < 63 ? 1.f : 0.f;
  const float* r0 = img + ym * 64;
  const float* r1 = img + y * 64;
  const float* r2 = img + yp * 64;
  float t0 = (wc[0] * mL) * r0[xm] + wc[1] * r0[x] + (wc[2] * mR) * r0[xp];
  float t1 = (wc[3] * mL) * r1[xm] + wc[4] * r1[x] + (wc[5] * mR) * r1[xp];
  float t2 = (wc[6] * mL) * r2[xm] + wc[7] * r2[x] + (wc[8] * mR) * r2[xp];
  out[t] = mT * t0 + t1 + mB * t2;
}

// ---------------------------------------------------------------------------
// K2: grid flat 1024 (b = bid&7, y = bid>>3), block 512.
//  Thread (x, q) computes 16 channels; branchless dw taps; writes sump row
//  (y+1) in [px][ch] layout via LDS transpose; in-block gate stats; ALSO
//  zeroes this row's px0/px129 borders (and rows 0/129 when y==0).
// ---------------------------------------------------------------------------
__global__ __launch_bounds__(512) void fuse_sum_stats_kernel(
    const float* __restrict__ low, const float* __restrict__ hsm,
    const float* __restrict__ wl, unsigned short* __restrict__ sump,
    float* __restrict__ gate_in) {
  __shared__ unsigned short sumS[128 * 64];  // 16 KB, XOR-swizzled
  __shared__ float sh[4][4][128];            // 8 KB stats

  const int bid = blockIdx.x;
  const int b = bid & 7;
  const int y = bid >> 3;
  const int tid = threadIdx.x;
  const int x = tid & 127;
  const int q = tid >> 7;
  char* sbase = (char*)sump + (size_t)b * SIMGB;

  // border zeroing
  {
    const short8v z = {0, 0, 0, 0, 0, 0, 0, 0};
    if (y == 0) {
      for (int i = tid; i < 2080; i += 512) {
        int row = (i < 1040) ? 0 : 129;
        int o = (i % 1040) * 16;
        *(short8v*)(sbase + (size_t)row * SROWB + o) = z;
      }
    }
    if (tid < 16) {
      int side = tid >> 3;
      int o = (tid & 7) * 16;
      *(short8v*)(sbase + (size_t)(y + 1) * SROWB + side * (129 * 128) + o) = z;
    }
  }

  // bilinear-up coords (64 -> 128, half-pixel)
  float sy = 0.5f * y - 0.25f;
  float sx = 0.5f * x - 0.25f;
  float y0f = floorf(sy), x0f = floorf(sx);
  float wy = sy - y0f, wx = sx - x0f;
  int iy0 = (int)y0f, ix0 = (int)x0f;
  int iy0c = max(0, min(HHH - 1, iy0));
  int iy1c = max(0, min(HHH - 1, iy0 + 1));
  int ix0c = max(0, min(HWW - 1, ix0));
  int ix1c = max(0, min(HWW - 1, ix0 + 1));
  float w00 = (1.f - wy) * (1.f - wx), w01 = (1.f - wy) * wx;
  float w10 = wy * (1.f - wx), w11 = wy * wx;

  const int xm = max(x - 1, 0), xp = min(x + 1, 127);
  const int ym = max(y - 1, 0), yp = min(y + 1, 127);
  const float mL = x > 0 ? 1.f : 0.f, mR = x < 127 ? 1.f : 0.f;
  const float mT = y > 0 ? 1.f : 0.f, mB = y < 127 ? 1.f : 0.f;

  float hmean = 0.f, lmean = 0.f;
  float hmax = -3.402823466e+38f, lmax = -3.402823466e+38f;

  unsigned short sv[16];
#pragma unroll 4
  for (int j = 0; j < 16; ++j) {
    const int c = q * 16 + j;
    const float* limg = low + ((size_t)(b * CC + c)) * (LHH * LWW);
    const float* wc = wl + c * 9;
    const float* r0 = limg + ym * 128;
    const float* r1 = limg + y * 128;
    const float* r2 = limg + yp * 128;
    float t0 = (wc[0] * mL) * r0[xm] + wc[1] * r0[x] + (wc[2] * mR) * r0[xp];
    float t1 = (wc[3] * mL) * r1[xm] + wc[4] * r1[x] + (wc[5] * mR) * r1[xp];
    float t2 = (wc[6] * mL) * r2[xm] + wc[7] * r2[x] + (wc[8] * mR) * r2[xp];
    float l = mT * t0 + t1 + mB * t2;

    const float* himg = hsm + ((size_t)(b * CC + c)) * (HHH * HWW);
    float h = w00 * himg[iy0c * HWW + ix0c] + w01 * himg[iy0c * HWW + ix1c] +
              w10 * himg[iy1c * HWW + ix0c] + w11 * himg[iy1c * HWW + ix1c];
    sv[j] = f2bf(l + h);
    hmean += h;
    lmean += l;
    hmax = fmaxf(hmax, h);
    lmax = fmaxf(lmax, l);
  }

  // pack 16 shorts -> two b128 LDS writes at swizzled addr
  {
    unsigned int pk[8];
#pragma unroll
    for (int j = 0; j < 8; ++j)
      pk[j] = (unsigned)sv[2 * j] | ((unsigned)sv[2 * j + 1] << 16);
    const int u0 = (x * 128 + q * 32) ^ ((x & 7) << 4);
    const int u1 = (x * 128 + q * 32 + 16) ^ ((x & 7) << 4);
    *(short8v*)((char*)sumS + u0) = *(short8v*)&pk[0];
    *(short8v*)((char*)sumS + u1) = *(short8v*)&pk[4];
  }
  sh[0][q][x] = hmean;
  sh[1][q][x] = lmean;
  sh[2][q][x] = hmax;
  sh[3][q][x] = lmax;
  __syncthreads();

  // coalesced write-out: 16 KB -> global row (y+1), px 1..128
  {
    char* dst = sbase + (size_t)(y + 1) * SROWB + 128;
#pragma unroll
    for (int pass = 0; pass < 2; ++pass) {
      int o = (tid + pass * 512) * 16;
      int L = o ^ (((o >> 7) & 7) << 4);
      *(short8v*)(dst + o) = *(const short8v*)((const char*)sumS + L);
    }
  }
  // stats reduce
  {
    const int s = q;
    float v0 = sh[s][0][x], v1 = sh[s][1][x], v2 = sh[s][2][x],
          v3 = sh[s][3][x];
    float r;
    if (s < 2)
      r = (v0 + v1 + v2 + v3) * (1.0f / CC);
    else
      r = fmaxf(fmaxf(v0, v1), fmaxf(v2, v3));
    gate_in[((size_t)(b * 4 + s)) * 16384 + y * 128 + x] = r;
  }
}

// ---------------------------------------------------------------------------
// branchless zero-padded bilinear with PAIR loads: 2 x dwordx2 instead of
// 4 x dword. x-taps are adjacent except at clamped edges; select components.
// ---------------------------------------------------------------------------
__device__ __forceinline__ float bilin0p(const float* __restrict__ img, int H,
                                         int W, float gx, float gy) {
  float x0f = floorf(gx), y0f = floorf(gy);
  float wx1 = gx - x0f, wy1 = gy - y0f;
  float wx0 = 1.f - wx1, wy0 = 1.f - wy1;
  int x0 = (int)x0f, y0 = (int)y0f;
  int y1 = y0 + 1;
  float mx0 = ((unsigned)x0 < (unsigned)W) ? wx0 : 0.f;
  float mx1 = ((unsigned)(x0 + 1) < (unsigned)W) ? wx1 : 0.f;
  float my0 = ((unsigned)y0 < (unsigned)H) ? wy0 : 0.f;
  float my1 = ((unsigned)y1 < (unsigned)H) ? wy1 : 0.f;
  int xb = min(max(x0, 0), W - 2);
  int y0c = min(max(y0, 0), H - 1);
  int y1c = min(max(y1, 0), H - 1);
  f2u p0 = *(const f2u*)(img + y0c * W + xb);
  f2u p1 = *(const f2u*)(img + y1c * W + xb);
  // v00: x0 in [0,W-2] -> p.x ; x0==W-1 -> p.y ; OOB -> weight 0
  // v01: x0 < 0 -> p.x (x1c==0) ; else p.y
  bool lo = (x0 == xb);
  bool neg = (x0 < 0);
  float v00 = lo ? p0.x : p0.y;
  float v01 = neg ? p0.x : p0.y;
  float v10 = lo ? p1.x : p1.y;
  float v11 = neg ? p1.x : p1.y;
  return my0 * (mx0 * v00 + mx1 * v01) + my1 * (mx0 * v10 + mx1 * v11);
}

// ---------------------------------------------------------------------------
// K4: fused gate-conv + flow-GEMM + warp + blend. grid flat 2048:
//  b = bid&7 (XCD), y = (bid>>3)&127, xh = bid>>10.
//  8 waves, each owns 32 oc' x 64 px (acc[4][2] -> 32 AGPR); stage the
//  3x66-px window once; barrier-free K-loop; combine from registers with
//  pair-load gathers.
// ---------------------------------------------------------------------------
__global__ __launch_bounds__(512, 6) void flow_gemm_combine_kernel(
    const unsigned short* __restrict__ sump,
    const unsigned short* __restrict__ bt, const float* __restrict__ low,
    const float* __restrict__ high, const float* __restrict__ gate_in,
    const float* __restrict__ wg, float* __restrict__ out) {
  __shared__ unsigned short ldsU[3 * 4224];  // 25344 B
  __shared__ float gateS[64];

  const int bid = blockIdx.x;
  const int b = bid & 7;
  const int y = (bid >> 3) & 127;
  const int xh = bid >> 10;
  const int tid = threadIdx.x;
  const int lane = tid & 63;
  const int wid = tid >> 6;  // oc' block = wid*32
  const int lr = lane & 15;
  const int lg = lane >> 4;

  // ---- stage rows y..y+2, px window xh*64 .. xh*64+65, XOR-swizzled
  {
    const char* src =
        (const char*)sump + (size_t)b * SIMGB + (size_t)y * SROWB + xh * 8192;
    char* dstb = (char*)ldsU;
    for (int i = tid; i < 1584; i += 512) {
      int seg = i / 528;
      int wo = (i - seg * 528) * 16;
      int o = seg * KROWB + wo;
      int L = o ^ (((o >> 7) & 7) << 4);
      *(short8v*)(dstb + L) = *(const short8v*)(src + seg * SROWB + wo);
    }
  }

  // ---- gate conv for this block's 64 px (wave 0), branchless
  if (tid < 64) {
    const int x = xh * 64 + tid;
    const int xm = max(x - 1, 0), xp = min(x + 1, 127);
    const int ym = max(y - 1, 0), yp = min(y + 1, 127);
    const float mL = x > 0 ? 1.f : 0.f, mR = x < 127 ? 1.f : 0.f;
    const float mT = y > 0 ? 1.f : 0.f, mB = y < 127 ? 1.f : 0.f;
    const float* gi = gate_in + (size_t)b * 4 * 16384;
    float acc0 = 0.f;
#pragma unroll
    for (int ic = 0; ic < 4; ++ic) {
      const float* img = gi + ic * 16384;
      const float* wc = wg + ic * 9;
      const float* r0 = img + ym * 128;
      const float* r1 = img + y * 128;
      const float* r2 = img + yp * 128;
      float t0 = (wc[0] * mL) * r0[xm] + wc[1] * r0[x] + (wc[2] * mR) * r0[xp];
      float t1 = (wc[3] * mL) * r1[xm] + wc[4] * r1[x] + (wc[5] * mR) * r1[xp];
      float t2 = (wc[6] * mL) * r2[xm] + wc[7] * r2[x] + (wc[8] * mR) * r2[xp];
      acc0 += mT * t0 + t1 + mB * t2;
    }
    gateS[tid] = 1.0f / (1.0f + expf(-acc0));
  }
  __syncthreads();

  f32x4 acc[4][2];
#pragma unroll
  for (int i = 0; i < 4; ++i)
#pragma unroll
    for (int j = 0; j < 2; ++j) acc[i][j] = (f32x4){0.f, 0.f, 0.f, 0.f};

  const char* rc = (const char*)ldsU;
  const unsigned short* btw = bt + (size_t)(wid * 32 + lr) * BTS + lg * 8;
  for (int dydx = 0; dydx < 9; ++dydx) {
    const int dy = dydx / 3;
    const int dxl = dydx - dy * 3;
#pragma unroll
    for (int cc = 0; cc < 2; ++cc) {
      short8v af[4], bfr[2];
#pragma unroll
      for (int mf = 0; mf < 4; ++mf) {
        const int p = dy * 66 + dxl + mf * 16 + lr;
        const int fa = (p * 128 + cc * 64 + lg * 16) ^ ((p & 7) << 4);
        af[mf] = *(const short8v*)(rc + fa);
      }
#pragma unroll
      for (int nf = 0; nf < 2; ++nf)
        bfr[nf] = *(const short8v*)&btw[nf * 16 * BTS + dydx * 64 + cc * 32];
      // swapped operands: D = [oc' x px]
#pragma unroll
      for (int mf = 0; mf < 4; ++mf)
#pragma unroll
        for (int nf = 0; nf < 2; ++nf)
          acc[mf][nf] = __builtin_amdgcn_mfma_f32_16x16x32_bf16(
              bfr[nf], af[mf], acc[mf][nf], 0, 0, 0);
    }
  }

  // ---- combine from registers: lane (lr,lg) frag (mf,nf) holds all 4 flow
  // components of (px = xh*64 + mf*16 + lr, c = wid*8 + nf*4 + lg)
  const float* lowb = low + (size_t)b * CC * 16384;
  const float* highb = high + (size_t)b * CC * 4096;
  float* outb = out + (size_t)b * CC * 16384;
  const float by = -1.0f + y * (2.0f / 127.0f);
  const float gyh_b = (by + 1.0f) * 31.5f;
  const float gyl_b = (by + 1.0f) * 63.5f;
  const int xg0 = xh * 64;

#pragma unroll
  for (int mf = 0; mf < 4; ++mf) {
    const int x = xg0 + mf * 16 + lr;
    const float g = gateS[mf * 16 + lr];
    const float bx = -1.0f + x * (2.0f / 127.0f);
    const float gxh_b = (bx + 1.0f) * 31.5f;
    const float gxl_b = (bx + 1.0f) * 63.5f;
#pragma unroll
    for (int nf = 0; nf < 2; ++nf) {
      const int c = wid * 8 + nf * 4 + lg;
      float gxh = fmaf(acc[mf][nf][0], 63.0f / 256.0f, gxh_b);
      float gyh = fmaf(acc[mf][nf][1], 63.0f / 256.0f, gyh_b);
      float hwv = bilin0p(highb + (size_t)c * 4096, HHH, HWW, gxh, gyh);

      float gxl = fmaf(acc[mf][nf][2], 127.0f / 256.0f, gxl_b);
      float gyl = fmaf(acc[mf][nf][3], 127.0f / 256.0f, gyl_b);
      float lwv = bilin0p(lowb + (size_t)c * 16384, LHH, LWW, gxl, gyl);

      outb[(size_t)c * 16384 + y * 128 + x] = fmaf(g, hwv - lwv, lwv);
    }
  }
}

// ---------------------------------------------------------------------------
extern "C" void kernel_launch(void* const* d_in, const int* in_sizes, int n_in,
                              void* d_out, int out_size, void* d_ws,
                              size_t ws_size, hipStream_t stream) {
  const float* low = (const float*)d_in[0];
  const float* high = (const float*)d_in[1];
  const float* w_conv_l = (const float*)d_in[2];
  const float* w_conv_h = (const float*)d_in[3];
  const float* w_flow = (const float*)d_in[4];
  const float* w_gate = (const float*)d_in[5];
  float* out = (float*)d_out;
  char* ws = (char*)d_ws;

  const size_t OFF_HSMALL = 0;         //  8,388,608
  const size_t OFF_SUMP = 8388608;     // 17,305,600 (bf16 [b][row][px][ch])
  const size_t OFF_GATEIN = 25694208;  //  2,097,152
  const size_t OFF_BT = 28315648;      //    299,008

  float* h_small = (float*)(ws + OFF_HSMALL);
  unsigned short* sump = (unsigned short*)(ws + OFF_SUMP);
  float* gate_in = (float*)(ws + OFF_GATEIN);
  unsigned short* bt = (unsigned short*)(ws + OFF_BT);

  // K1: dw-high (8192 blocks) + prep_bt (584 blocks appended)
  dw_high_prep_kernel<<<8192 + 584, 256, 0, stream>>>(high, w_conv_h, h_small,
                                                      w_flow, bt);
  // K2: sum + stats + sump borders
  fuse_sum_stats_kernel<<<1024, 512, 0, stream>>>(low, h_small, w_conv_l, sump,
                                                  gate_in);
  // K4: gate conv + flow GEMM + warp + blend
  flow_gemm_combine_kernel<<<2048, 512, 0, stream>>>(sump, bt, low, high,
                                                     gate_in, w_gate, out);
}

// Round 9
// 130.654 us; speedup vs baseline: 9.2399x; 1.0448x over previous
//
#include <hip/hip_runtime.h>
#include <math.h>

#define BB 8
#define CC 64
#define LHH 128
#define LWW 128
#define HHH 64
#define HWW 64

typedef __attribute__((ext_vector_type(8))) short short8v;
typedef __attribute__((ext_vector_type(4))) float f32x4;

// unaligned-capable float pair (align 4)
typedef struct __attribute__((packed, aligned(4))) {
  float x, y;
} f2u;

#define BTS 584   // B_t row stride (shorts): 576 + 8 pad
// sump layout: [b][row:130][px:130][ch:64] bf16; row = 8320 shorts = 16640 B
#define SROWB 16640          // bytes per global row
#define SIMGB (130 * SROWB)  // bytes per image
#define KROWB 8448           // K4 LDS row stride: 66 px * 128 B

__device__ __forceinline__ unsigned short f2bf(float f) {
  unsigned u = __float_as_uint(f);
  unsigned r = (u + 0x7fffu + ((u >> 16) & 1u)) >> 16;
  return (unsigned short)r;
}

// ---------------------------------------------------------------------------
// K1: depthwise 3x3 on high_feature -> h_small (branchless), PLUS (appended
//  blocks) prep of B_t[oc'][k] bf16: oc' = c*4+j, orig = (j>>1)*128+2c+(j&1),
//  k = (dy*3+dx)*64 + ci.
// ---------------------------------------------------------------------------
__global__ __launch_bounds__(256) void dw_high_prep_kernel(
    const float* __restrict__ hf, const float* __restrict__ w,
    float* __restrict__ out, const float* __restrict__ wflow,
    unsigned short* __restrict__ bt) {
  if (blockIdx.x >= 8192) {  // prep_bt part
    int t = (blockIdx.x - 8192) * 256 + threadIdx.x;
    if (t >= 256 * BTS) return;
    int oc2 = t / BTS;
    int kd = t - oc2 * BTS;
    unsigned short v = 0;
    if (kd < 576) {
      int c = oc2 >> 2;
      int j = oc2 & 3;
      int orig = (j >> 1) * 128 + 2 * c + (j & 1);
      int dydx = kd >> 6;
      int ci = kd & 63;
      v = f2bf(wflow[(orig * 64 + ci) * 9 + dydx]);
    }
    bt[t] = v;
    return;
  }
  int t = blockIdx.x * 256 + threadIdx.x;
  int x = t & 63;
  int y = (t >> 6) & 63;
  int c = (t >> 12) & 63;
  int b = t >> 18;
  const float* img = hf + ((size_t)(b * CC + c)) * (HHH * HWW);
  const float* wc = w + c * 9;
  const int xm = max(x - 1, 0), xp = min(x + 1, 63);
  const int ym = max(y - 1, 0), yp = min(y + 1, 63);
  const float mL = x > 0 ? 1.f : 0.f, mR = x < 63 ? 1.f : 0.f;
  const float mT = y > 0 ? 1.f : 0.f, mB = y < 63 ? 1.f : 0.f;
  const float* r0 = img + ym * 64;
  const float* r1 = img + y * 64;
  const float* r2 = img + yp * 64;
  float t0 = (wc[0] * mL) * r0[xm] + wc[1] * r0[x] + (wc[2] * mR) * r0[xp];
  float t1 = (wc[3] * mL) * r1[xm] + wc[4] * r1[x] + (wc[5] * mR) * r1[xp];
  float t2 = (wc[6] * mL) * r2[xm] + wc[7] * r2[x] + (wc[8] * mR) * r2[xp];
  out[t] = mT * t0 + t1 + mB * t2;
}

// ---------------------------------------------------------------------------
// K2: grid flat 1024 (b = bid&7, y = bid>>3), block 512.
//  Thread (x, q) computes 16 channels; pair-load dw taps + pair-load hsm
//  bilinear (u32 saddr offsets); writes sump row (y+1) in [px][ch] layout
//  via LDS transpose; in-block gate stats; zeroes borders.
// ---------------------------------------------------------------------------
__global__ __launch_bounds__(512) void fuse_sum_stats_kernel(
    const float* __restrict__ low, const float* __restrict__ hsm,
    const float* __restrict__ wl, unsigned short* __restrict__ sump,
    float* __restrict__ gate_in) {
  __shared__ unsigned short sumS[128 * 64];  // 16 KB, XOR-swizzled
  __shared__ float sh[4][4][128];            // 8 KB stats

  const int bid = blockIdx.x;
  const int b = bid & 7;
  const int y = bid >> 3;
  const int tid = threadIdx.x;
  const int x = tid & 127;
  const int q = tid >> 7;
  char* sbase = (char*)sump + (size_t)b * SIMGB;

  // border zeroing
  {
    const short8v z = {0, 0, 0, 0, 0, 0, 0, 0};
    if (y == 0) {
      for (int i = tid; i < 2080; i += 512) {
        int row = (i < 1040) ? 0 : 129;
        int o = (i % 1040) * 16;
        *(short8v*)(sbase + (size_t)row * SROWB + o) = z;
      }
    }
    if (tid < 16) {
      int side = tid >> 3;
      int o = (tid & 7) * 16;
      *(short8v*)(sbase + (size_t)(y + 1) * SROWB + side * (129 * 128) + o) = z;
    }
  }

  // bilinear-up coords (64 -> 128, half-pixel)
  float sy = 0.5f * y - 0.25f;
  float sx = 0.5f * x - 0.25f;
  float y0f = floorf(sy), x0f = floorf(sx);
  float wy = sy - y0f, wx = sx - x0f;
  int iy0 = (int)y0f, ix0 = (int)x0f;
  int iy0c = max(0, min(HHH - 1, iy0));
  int iy1c = max(0, min(HHH - 1, iy0 + 1));
  float w00 = (1.f - wy) * (1.f - wx), w01 = (1.f - wy) * wx;
  float w10 = wy * (1.f - wx), w11 = wy * wx;
  const int hxb = min(max(ix0, 0), HWW - 2);
  const bool hs0 = (ix0 <= hxb);
  const bool hs1 = (ix0 + 1 <= hxb);

  const int xm = max(x - 1, 0), xp = min(x + 1, 127);
  const int ym = max(y - 1, 0), yp = min(y + 1, 127);
  const float mL = x > 0 ? 1.f : 0.f, mR = x < 127 ? 1.f : 0.f;
  const float mT = y > 0 ? 1.f : 0.f, mB = y < 127 ? 1.f : 0.f;
  const bool xz = (x == 0);

  const unsigned lco = (unsigned)((b * CC + q * 16) * 16384);
  const unsigned hco = (unsigned)((b * CC + q * 16) * 4096);
  const unsigned ro0 = (unsigned)(ym * 128 + xm);
  const unsigned ro1 = (unsigned)(y * 128 + xm);
  const unsigned ro2 = (unsigned)(yp * 128 + xm);
  const unsigned dxp = (unsigned)(xp - xm);
  const unsigned ho0 = (unsigned)(iy0c * 64 + hxb);
  const unsigned ho1 = (unsigned)(iy1c * 64 + hxb);

  float hmean = 0.f, lmean = 0.f;
  float hmax = -3.402823466e+38f, lmax = -3.402823466e+38f;

  unsigned short sv[16];
#pragma unroll 4
  for (int j = 0; j < 16; ++j) {
    const unsigned lo_ = lco + (unsigned)(j * 16384);
    const float* wc = wl + (q * 16 + j) * 9;
    f2u p0 = *(const f2u*)(low + (lo_ + ro0));
    f2u p1 = *(const f2u*)(low + (lo_ + ro1));
    f2u p2 = *(const f2u*)(low + (lo_ + ro2));
    float r0p = low[lo_ + ro0 + dxp];
    float r1p = low[lo_ + ro1 + dxp];
    float r2p = low[lo_ + ro2 + dxp];
    float r0x = xz ? p0.x : p0.y;
    float r1x = xz ? p1.x : p1.y;
    float r2x = xz ? p2.x : p2.y;
    float t0 = (wc[0] * mL) * p0.x + wc[1] * r0x + (wc[2] * mR) * r0p;
    float t1 = (wc[3] * mL) * p1.x + wc[4] * r1x + (wc[5] * mR) * r1p;
    float t2 = (wc[6] * mL) * p2.x + wc[7] * r2x + (wc[8] * mR) * r2p;
    float l = mT * t0 + t1 + mB * t2;

    const unsigned ho_ = hco + (unsigned)(j * 4096);
    f2u q0 = *(const f2u*)(hsm + (ho_ + ho0));
    f2u q1 = *(const f2u*)(hsm + (ho_ + ho1));
    float h00 = hs0 ? q0.x : q0.y;
    float h01 = hs1 ? q0.x : q0.y;
    float h10 = hs0 ? q1.x : q1.y;
    float h11 = hs1 ? q1.x : q1.y;
    float h = w00 * h00 + w01 * h01 + w10 * h10 + w11 * h11;

    sv[j] = f2bf(l + h);
    hmean += h;
    lmean += l;
    hmax = fmaxf(hmax, h);
    lmax = fmaxf(lmax, l);
  }

  // pack 16 shorts -> two b128 LDS writes at swizzled addr
  {
    unsigned int pk[8];
#pragma unroll
    for (int j = 0; j < 8; ++j)
      pk[j] = (unsigned)sv[2 * j] | ((unsigned)sv[2 * j + 1] << 16);
    const int u0 = (x * 128 + q * 32) ^ ((x & 7) << 4);
    const int u1 = (x * 128 + q * 32 + 16) ^ ((x & 7) << 4);
    *(short8v*)((char*)sumS + u0) = *(short8v*)&pk[0];
    *(short8v*)((char*)sumS + u1) = *(short8v*)&pk[4];
  }
  sh[0][q][x] = hmean;
  sh[1][q][x] = lmean;
  sh[2][q][x] = hmax;
  sh[3][q][x] = lmax;
  __syncthreads();

  // coalesced write-out: 16 KB -> global row (y+1), px 1..128
  {
    char* dst = sbase + (size_t)(y + 1) * SROWB + 128;
#pragma unroll
    for (int pass = 0; pass < 2; ++pass) {
      int o = (tid + pass * 512) * 16;
      int L = o ^ (((o >> 7) & 7) << 4);
      *(short8v*)(dst + o) = *(const short8v*)((const char*)sumS + L);
    }
  }
  // stats reduce
  {
    const int s = q;
    float v0 = sh[s][0][x], v1 = sh[s][1][x], v2 = sh[s][2][x],
          v3 = sh[s][3][x];
    float r;
    if (s < 2)
      r = (v0 + v1 + v2 + v3) * (1.0f / CC);
    else
      r = fmaxf(fmaxf(v0, v1), fmaxf(v2, v3));
    gate_in[((size_t)(b * 4 + s)) * 16384 + y * 128 + x] = r;
  }
}

// ---------------------------------------------------------------------------
// batched branchless bilinear: prep (addresses+weights+2 pair loads) is
// separated from fin (arithmetic) so multiple samples' loads pipeline.
// Uses uniform base + u32 element offset (saddr form).
// ---------------------------------------------------------------------------
struct BSamp {
  f2u p0, p1;
  float mx0, mx1, my0, my1;
  bool s0, s1;
};

__device__ __forceinline__ BSamp bprep(const float* __restrict__ base,
                                       unsigned coff, int H, int W, float gx,
                                       float gy) {
  BSamp s;
  float x0f = floorf(gx), y0f = floorf(gy);
  float wx1 = gx - x0f, wy1 = gy - y0f;
  int x0 = (int)x0f, y0 = (int)y0f;
  int y1 = y0 + 1;
  s.mx0 = ((unsigned)x0 < (unsigned)W) ? 1.f - wx1 : 0.f;
  s.mx1 = ((unsigned)(x0 + 1) < (unsigned)W) ? wx1 : 0.f;
  s.my0 = ((unsigned)y0 < (unsigned)H) ? 1.f - wy1 : 0.f;
  s.my1 = ((unsigned)y1 < (unsigned)H) ? wy1 : 0.f;
  int xb = min(max(x0, 0), W - 2);
  int y0c = min(max(y0, 0), H - 1);
  int y1c = min(max(y1, 0), H - 1);
  s.p0 = *(const f2u*)(base + (coff + (unsigned)(y0c * W + xb)));
  s.p1 = *(const f2u*)(base + (coff + (unsigned)(y1c * W + xb)));
  s.s0 = (x0 <= xb);
  s.s1 = (x0 + 1 <= xb);
  return s;
}

__device__ __forceinline__ float bfin(const BSamp& s) {
  float v00 = s.s0 ? s.p0.x : s.p0.y;
  float v01 = s.s1 ? s.p0.x : s.p0.y;
  float v10 = s.s0 ? s.p1.x : s.p1.y;
  float v11 = s.s1 ? s.p1.x : s.p1.y;
  return s.my0 * (s.mx0 * v00 + s.mx1 * v01) +
         s.my1 * (s.mx0 * v10 + s.mx1 * v11);
}

// ---------------------------------------------------------------------------
// K4: fused gate-conv + flow-GEMM + warp + blend. grid flat 2048:
//  b = bid&7 (XCD), y = (bid>>3)&127, xh = bid>>10.
//  8 waves, each owns 32 oc' x 64 px (acc[4][2]); launch_bounds(512,4) gives
//  the register budget to keep 8 gather pair-loads in flight per mf-step.
// ---------------------------------------------------------------------------
__global__ __launch_bounds__(512, 4) void flow_gemm_combine_kernel(
    const unsigned short* __restrict__ sump,
    const unsigned short* __restrict__ bt, const float* __restrict__ low,
    const float* __restrict__ high, const float* __restrict__ gate_in,
    const float* __restrict__ wg, float* __restrict__ out) {
  __shared__ unsigned short ldsU[3 * 4224];  // 25344 B
  __shared__ float gateS[64];

  const int bid = blockIdx.x;
  const int b = bid & 7;
  const int y = (bid >> 3) & 127;
  const int xh = bid >> 10;
  const int tid = threadIdx.x;
  const int lane = tid & 63;
  const int wid = tid >> 6;  // oc' block = wid*32
  const int lr = lane & 15;
  const int lg = lane >> 4;

  // ---- stage rows y..y+2, px window xh*64 .. xh*64+65, XOR-swizzled
  {
    const char* src =
        (const char*)sump + (size_t)b * SIMGB + (size_t)y * SROWB + xh * 8192;
    char* dstb = (char*)ldsU;
#pragma unroll
    for (int pass = 0; pass < 3; ++pass) {
      int i = tid + pass * 512;
      int seg = i / 528;
      int wo = (i - seg * 528) * 16;
      int o = seg * KROWB + wo;
      int L = o ^ (((o >> 7) & 7) << 4);
      *(short8v*)(dstb + L) = *(const short8v*)(src + seg * SROWB + wo);
    }
    if (tid < 48) {
      int i = tid + 1536;
      int seg = i / 528;
      int wo = (i - seg * 528) * 16;
      int o = seg * KROWB + wo;
      int L = o ^ (((o >> 7) & 7) << 4);
      *(short8v*)(dstb + L) = *(const short8v*)(src + seg * SROWB + wo);
    }
  }

  // ---- gate conv for this block's 64 px (wave 0), branchless
  if (tid < 64) {
    const int x = xh * 64 + tid;
    const int xm = max(x - 1, 0), xp = min(x + 1, 127);
    const int ym = max(y - 1, 0), yp = min(y + 1, 127);
    const float mL = x > 0 ? 1.f : 0.f, mR = x < 127 ? 1.f : 0.f;
    const float mT = y > 0 ? 1.f : 0.f, mB = y < 127 ? 1.f : 0.f;
    const float* gi = gate_in + (size_t)b * 4 * 16384;
    float acc0 = 0.f;
#pragma unroll
    for (int ic = 0; ic < 4; ++ic) {
      const float* img = gi + ic * 16384;
      const float* wc = wg + ic * 9;
      const float* r0 = img + ym * 128;
      const float* r1 = img + y * 128;
      const float* r2 = img + yp * 128;
      float t0 = (wc[0] * mL) * r0[xm] + wc[1] * r0[x] + (wc[2] * mR) * r0[xp];
      float t1 = (wc[3] * mL) * r1[xm] + wc[4] * r1[x] + (wc[5] * mR) * r1[xp];
      float t2 = (wc[6] * mL) * r2[xm] + wc[7] * r2[x] + (wc[8] * mR) * r2[xp];
      acc0 += mT * t0 + t1 + mB * t2;
    }
    gateS[tid] = 1.0f / (1.0f + expf(-acc0));
  }
  __syncthreads();

  f32x4 acc[4][2];
#pragma unroll
  for (int i = 0; i < 4; ++i)
#pragma unroll
    for (int j = 0; j < 2; ++j) acc[i][j] = (f32x4){0.f, 0.f, 0.f, 0.f};

  const char* rc = (const char*)ldsU;
  const unsigned short* btw = bt + (size_t)(wid * 32 + lr) * BTS + lg * 8;
  for (int dydx = 0; dydx < 9; ++dydx) {
    const int dy = dydx / 3;
    const int dxl = dydx - dy * 3;
#pragma unroll
    for (int cc = 0; cc < 2; ++cc) {
      short8v af[4], bfr[2];
#pragma unroll
      for (int mf = 0; mf < 4; ++mf) {
        const int p = dy * 66 + dxl + mf * 16 + lr;
        const int fa = (p * 128 + cc * 64 + lg * 16) ^ ((p & 7) << 4);
        af[mf] = *(const short8v*)(rc + fa);
      }
#pragma unroll
      for (int nf = 0; nf < 2; ++nf)
        bfr[nf] = *(const short8v*)&btw[nf * 16 * BTS + dydx * 64 + cc * 32];
      // swapped operands: D = [oc' x px]
#pragma unroll
      for (int mf = 0; mf < 4; ++mf)
#pragma unroll
        for (int nf = 0; nf < 2; ++nf)
          acc[mf][nf] = __builtin_amdgcn_mfma_f32_16x16x32_bf16(
              bfr[nf], af[mf], acc[mf][nf], 0, 0, 0);
    }
  }

  // ---- combine from registers: lane (lr,lg) frag (mf,nf) holds all 4 flow
  // components of (px = xh*64 + mf*16 + lr, c = wid*8 + nf*4 + lg).
  // All 4 samples of an mf-step are prepped (8 pair loads) before any fin.
  const float* lowb = low + (size_t)b * CC * 16384;
  const float* highb = high + (size_t)b * CC * 4096;
  float* outb = out + (size_t)b * CC * 16384;
  const float by = -1.0f + y * (2.0f / 127.0f);
  const float gyh_b = (by + 1.0f) * 31.5f;
  const float gyl_b = (by + 1.0f) * 63.5f;
  const int xg0 = xh * 64;
  const int c0 = wid * 8 + lg;
  const int c1 = c0 + 4;

#pragma unroll
  for (int mf = 0; mf < 4; ++mf) {
    const int x = xg0 + mf * 16 + lr;
    const float g = gateS[mf * 16 + lr];
    const float bx = -1.0f + x * (2.0f / 127.0f);
    const float gxh_b = (bx + 1.0f) * 31.5f;
    const float gxl_b = (bx + 1.0f) * 63.5f;

    BSamp sh0 = bprep(highb, (unsigned)(c0 * 4096), HHH, HWW,
                      fmaf(acc[mf][0][0], 63.0f / 256.0f, gxh_b),
                      fmaf(acc[mf][0][1], 63.0f / 256.0f, gyh_b));
    BSamp sl0 = bprep(lowb, (unsigned)(c0 * 16384), LHH, LWW,
                      fmaf(acc[mf][0][2], 127.0f / 256.0f, gxl_b),
                      fmaf(acc[mf][0][3], 127.0f / 256.0f, gyl_b));
    BSamp sh1 = bprep(highb, (unsigned)(c1 * 4096), HHH, HWW,
                      fmaf(acc[mf][1][0], 63.0f / 256.0f, gxh_b),
                      fmaf(acc[mf][1][1], 63.0f / 256.0f, gyh_b));
    BSamp sl1 = bprep(lowb, (unsigned)(c1 * 16384), LHH, LWW,
                      fmaf(acc[mf][1][2], 127.0f / 256.0f, gxl_b),
                      fmaf(acc[mf][1][3], 127.0f / 256.0f, gyl_b));

    float h0 = bfin(sh0), l0 = bfin(sl0);
    outb[(unsigned)(c0 * 16384 + y * 128 + x)] = fmaf(g, h0 - l0, l0);
    float h1 = bfin(sh1), l1 = bfin(sl1);
    outb[(unsigned)(c1 * 16384 + y * 128 + x)] = fmaf(g, h1 - l1, l1);
  }
}

// ---------------------------------------------------------------------------
extern "C" void kernel_launch(void* const* d_in, const int* in_sizes, int n_in,
                              void* d_out, int out_size, void* d_ws,
                              size_t ws_size, hipStream_t stream) {
  const float* low = (const float*)d_in[0];
  const float* high = (const float*)d_in[1];
  const float* w_conv_l = (const float*)d_in[2];
  const float* w_conv_h = (const float*)d_in[3];
  const float* w_flow = (const float*)d_in[4];
  const float* w_gate = (const float*)d_in[5];
  float* out = (float*)d_out;
  char* ws = (char*)d_ws;

  const size_t OFF_HSMALL = 0;         //  8,388,608
  const size_t OFF_SUMP = 8388608;     // 17,305,600 (bf16 [b][row][px][ch])
  const size_t OFF_GATEIN = 25694208;  //  2,097,152
  const size_t OFF_BT = 28315648;      //    299,008

  float* h_small = (float*)(ws + OFF_HSMALL);
  unsigned short* sump = (unsigned short*)(ws + OFF_SUMP);
  float* gate_in = (float*)(ws + OFF_GATEIN);
  unsigned short* bt = (unsigned short*)(ws + OFF_BT);

  // K1: dw-high (8192 blocks) + prep_bt (584 blocks appended)
  dw_high_prep_kernel<<<8192 + 584, 256, 0, stream>>>(high, w_conv_h, h_small,
                                                      w_flow, bt);
  // K2: sum + stats + sump borders
  fuse_sum_stats_kernel<<<1024, 512, 0, stream>>>(low, h_small, w_conv_l, sump,
                                                  gate_in);
  // K4: gate conv + flow GEMM + warp + blend
  flow_gemm_combine_kernel<<<2048, 512, 0, stream>>>(sump, bt, low, high,
                                                     gate_in, w_gate, out);
}